// Round 9
// baseline (1060.029 us; speedup 1.0000x reference)
//
#include <hip/hip_runtime.h>
#include <cmath>

typedef unsigned short u16;
typedef unsigned int   u32;

using bf16x8 = __attribute__((ext_vector_type(8))) short;   // 8 bf16 in 4 VGPRs
using f32x4  = __attribute__((ext_vector_type(4))) float;

#define S_LEN 2048
#define NHEAD 32
#define HDIM  160
#define HID   5120   // NHEAD*HDIM
#define NQKV  15360  // HID + 2*HID

__device__ __forceinline__ f32x4 mfma16(bf16x8 a, bf16x8 b, f32x4 c) {
  return __builtin_amdgcn_mfma_f32_16x16x32_bf16(a, b, c, 0, 0, 0);
}

__device__ __forceinline__ u16 f2bf(float f) {          // RNE f32->bf16
  u32 u = __builtin_bit_cast(u32, f);
  u += 0x7FFFu + ((u >> 16) & 1u);
  return (u16)(u >> 16);
}
__device__ __forceinline__ float bf2f(u16 h) {
  u32 u = ((u32)h) << 16;
  return __builtin_bit_cast(float, u);
}
__device__ __forceinline__ bf16x8 cvt8(float4 a, float4 b) {  // 8 f32 -> bf16x8 (RNE)
  bf16x8 r;
  r[0] = (short)f2bf(a.x); r[1] = (short)f2bf(a.y);
  r[2] = (short)f2bf(a.z); r[3] = (short)f2bf(a.w);
  r[4] = (short)f2bf(b.x); r[5] = (short)f2bf(b.y);
  r[6] = (short)f2bf(b.z); r[7] = (short)f2bf(b.w);
  return r;
}

// async global->LDS, 16B per lane; LDS dest is wave-uniform base + lane*16
__device__ __forceinline__ void gload16(const void* g, void* l) {
  __builtin_amdgcn_global_load_lds((const __attribute__((address_space(1))) void*)g,
                                   (__attribute__((address_space(3))) void*)l, 16, 0, 0);
}

// ---------------- f32 -> bf16 convert (hs only now) ---------------------------
__global__ void cvt_bf16_kernel(const float* __restrict__ in, u16* __restrict__ out, int n8) {
  int i = blockIdx.x * 256 + threadIdx.x;
  if (i >= n8) return;
  const float4* p = (const float4*)in + (size_t)i * 2;
  float4 a = p[0], b = p[1];
  uint4 o;
  o.x = (u32)f2bf(a.x) | ((u32)f2bf(a.y) << 16);
  o.y = (u32)f2bf(a.z) | ((u32)f2bf(a.w) << 16);
  o.z = (u32)f2bf(b.x) | ((u32)f2bf(b.y) << 16);
  o.w = (u32)f2bf(b.z) | ((u32)f2bf(b.w) << 16);
  ((uint4*)out)[i] = o;
}

// ---------------- RoPE table: tab[s][j] = (cos, sin), j<80 -------------------
// eff=8192 -> mscale=1.0, ntk_alpha=3, base=10000*3^(160/158).
__global__ void rope_table_kernel(float2* __restrict__ tab) {
  __shared__ double invf_s[80];
  int tid = threadIdx.x;
  if (tid < 80) {
    double base = 10000.0 * pow(3.0, 160.0 / 158.0);
    invf_s[tid] = pow(base, -((double)(2 * tid)) / 160.0);
  }
  __syncthreads();
  for (int i = blockIdx.x * 256 + tid; i < S_LEN * 80; i += gridDim.x * 256) {
    int s = i / 80, j = i % 80;
    double ang = fmod((double)s * invf_s[j], 6.283185307179586476925287);
    float a = (float)ang;
    tab[i] = make_float2(cosf(a), sinf(a));
  }
}

// ---------------- RoPE apply + head-major relayout ---------------------------
__global__ void rope_apply_kernel(const u16* __restrict__ src, const float2* __restrict__ tab,
                                  u16* __restrict__ dst, int headStride, int rowStride) {
  int i = blockIdx.x * 256 + threadIdx.x;           // over 2048*32*80 dword-pairs
  if (i >= S_LEN * NHEAD * 80) return;
  int dp = i % 80; int sh = i / 80; int h = sh % NHEAD; int s = sh / NHEAD;
  int d = 2 * dp;
  const u16* row = src + (size_t)s * rowStride + h * headStride;
  u32 q01 = *(const u32*)&row[d];
  u32 p01 = *(const u32*)&row[d < 80 ? d + 80 : d - 80];
  int j = (d < 80) ? d : d - 80;
  float2 cs0 = tab[s * 80 + j];
  float2 cs1 = tab[s * 80 + j + 1];
  float q0 = bf2f((u16)(q01 & 0xffff)), q1 = bf2f((u16)(q01 >> 16));
  float p0 = bf2f((u16)(p01 & 0xffff)), p1 = bf2f((u16)(p01 >> 16));
  float sgn = (d < 80) ? -1.f : 1.f;                // out = x*cos + rot_half(x)*sin
  float o0 = q0 * cs0.x + sgn * p0 * cs0.y;
  float o1 = q1 * cs1.x + sgn * p1 * cs1.y;
  u32 o = (u32)f2bf(o0) | ((u32)f2bf(o1) << 16);
  *(u32*)&dst[((size_t)h * S_LEN + s) * HDIM + d] = o;
}

// ---------------- V transpose: v-slice of fused QKV -> Vt[h][d][s] -----------
__global__ void vtrans_kernel(const u16* __restrict__ src, u16* __restrict__ Vt, int rowStride) {
  __shared__ u16 T[HDIM][72];                       // pad 64->72 (2-way max on reads)
  int h = blockIdx.y; int s0 = blockIdx.x * 64; int tid = threadIdx.x;
  for (int i = tid; i < 64 * 80; i += 256) {
    int s = i / 80, dp = i % 80;
    u32 v = *(const u32*)&src[(size_t)(s0 + s) * rowStride + h * 320 + 2 * dp];
    T[2 * dp][s]     = (u16)(v & 0xffff);
    T[2 * dp + 1][s] = (u16)(v >> 16);
  }
  __syncthreads();
  for (int i = tid; i < HDIM * 32; i += 256) {
    int d = i / 32, sp = i % 32;
    u32 v = (u32)T[d][2 * sp] | ((u32)T[d][2 * sp + 1] << 16);
    *(u32*)&Vt[((size_t)h * HDIM + d) * S_LEN + s0 + 2 * sp] = v;
  }
}

// ---------------- GEMM 256x256, 8-phase + fused f32 B-conversion --------------
// C = A(bf16)[M,K] @ B(f32 weights)[N,K]^T, f32 acc, bf16 C out.
// R8 schedule (kk-major units, 4 phases/K-tile, setprio, 0 bank conflicts) with
// B reg-staged from f32: global_load_dwordx4 -> RNE cvt -> ds_write_b128 to the
// same slots gload_lds used (slot = tid*8; element-indexed swizzle unchanged).
// Single B reg-set (16 VGPR), prefetch distance 2 phases. vmcnt ledger:
//   steady outstanding cycle (oldest first): A0(k+1)[2] B0(k+1)[4] A1(k+1)[2]
//   -> ph1 vmcnt(2) drains A0+B0; write B0; load B1(k+1)[4]; ph2 +A0(k+2)[2]
//   -> ph3 vmcnt(2) drains A1+B1; write B1; load B0(k+2)[4]; ph0 +A1(k+2)[2].
// Tails: ph3 uses vmcnt(0) when kt+2>=NT (drains A1(kt+1) too).
__global__ __launch_bounds__(512, 2) void gemm256_qkv(
    const u16* __restrict__ A, const float* __restrict__ Bq, const float* __restrict__ Bkv,
    u16* __restrict__ Cout, int M, int N, int K)
{
  __shared__ u16 As[2][2][8192];   // [dbuf][kk][256*32]  64 KB
  __shared__ u16 Bs[2][2][8192];   // 64 KB
  int tid = threadIdx.x;
  int w = tid >> 6, l = tid & 63, l15 = l & 15, l4 = l >> 4;
  int wr = w >> 2, wc = w & 3;

  // XCD chunked swizzle (nwg % 8 == 0 guaranteed by launch)
  int nbx = gridDim.x;
  int nwg = nbx * gridDim.y;
  int lin = blockIdx.y * nbx + blockIdx.x;
  int cpx = nwg >> 3;
  int swz = (lin & 7) * cpx + (lin >> 3);
  int bm = (swz / nbx) * 256, bn = (swz % nbx) * 256;

  int srow = tid >> 2;                                  // 0..127
  int scol = ((tid & 3) * 8) ^ ((srow & 8) ? 16 : 0);   // pre-swizzled source col
  const u16* gAr = A + (size_t)(bm + srow) * K + scol;
  // B block lies entirely in Wq or Wkv (bn%256==0, HID%256==0)
  const float* Bsrc = (bn < HID) ? Bq + (size_t)bn * K : Bkv + (size_t)(bn - HID) * K;
  const float* gBa = Bsrc + (size_t)srow * K + scol;
  const float* gBb = gBa + (size_t)128 * K;
  int w512 = w * 512;                                   // wave-uniform dest (elems)

  f32x4 acc[8][4];
#pragma unroll
  for (int i = 0; i < 8; i++)
#pragma unroll
    for (int j = 0; j < 4; j++) acc[i][j] = f32x4{0.f, 0.f, 0.f, 0.f};

  int cA = (l4 * 8) ^ ((l15 & 8) ? 16 : 0);             // read-side swizzle (const)
  const int NT = K >> 6;                                // 80
  int arow = wr * 128;
  int brow = (wc >> 1) * 128 + (wc & 1) * 64;

  auto STA = [&](int kt, int kk) { int p = kt & 1, ko = (kt << 6) + (kk << 5);
    gload16(gAr + ko, &As[p][kk][w512]);
    gload16(gAr + (size_t)128 * K + ko, &As[p][kk][4096 + w512]); };

  float4 s0, s1, s2, s3;                                // B reg set (16 VGPR)
#define LDB(kt, kk) { int ko = ((kt) << 6) + ((kk) << 5);                      \
    s0 = *(const float4*)(gBa + ko); s1 = *(const float4*)(gBa + ko + 4);      \
    s2 = *(const float4*)(gBb + ko); s3 = *(const float4*)(gBb + ko + 4); }
#define WRB(pp, kk) {                                                          \
    *(bf16x8*)&Bs[pp][kk][tid * 8]        = cvt8(s0, s1);                      \
    *(bf16x8*)&Bs[pp][kk][4096 + tid * 8] = cvt8(s2, s3); }

  // ---- prologue: tile0 B written serially, tile0 A + tile1's A0,B0 in flight
  LDB(0, 0);
  asm volatile("s_waitcnt vmcnt(0)" ::: "memory");
  WRB(0, 0);
  LDB(0, 1);
  asm volatile("s_waitcnt vmcnt(0)" ::: "memory");
  WRB(0, 1);
  STA(0, 0); STA(0, 1);          // [4 vm]
  STA(1, 0);                     // A0(1) [2]  (NT >= 2 always here)
  LDB(1, 0);                     // B0(1) [4]
  asm volatile("s_waitcnt vmcnt(6)" ::: "memory");   // tile0 A landed
  asm volatile("s_waitcnt lgkmcnt(0)" ::: "memory"); // tile0 B writes visible
  __builtin_amdgcn_s_barrier();

  bf16x8 aF[4], bF0[4], bF1[4];

  for (int kt = 0; kt < NT; ++kt) {
    int p = kt & 1;

    // ---- ph0: kk0, mi 0-3
    if (kt + 1 < NT) STA(kt + 1, 1);                  // A1(kt+1) [2]
#pragma unroll
    for (int mi = 0; mi < 4; ++mi)
      aF[mi] = *(const bf16x8*)&As[p][0][(arow + mi * 16 + l15) * 32 + cA];
#pragma unroll
    for (int ni = 0; ni < 4; ++ni)
      bF0[ni] = *(const bf16x8*)&Bs[p][0][(brow + ni * 16 + l15) * 32 + cA];
    __builtin_amdgcn_s_barrier();
    __builtin_amdgcn_s_setprio(1);
#pragma unroll
    for (int mi = 0; mi < 4; ++mi)
#pragma unroll
      for (int ni = 0; ni < 4; ++ni)
        acc[mi][ni] = mfma16(aF[mi], bF0[ni], acc[mi][ni]);
    __builtin_amdgcn_s_setprio(0);
    __builtin_amdgcn_s_barrier();

    // ---- ph1: kk0, mi 4-7 ; write B0(kt+1), load B1(kt+1)
    if (kt + 1 < NT) {
      asm volatile("s_waitcnt vmcnt(2)" ::: "memory");  // B0(kt+1) regs ready
      WRB(p ^ 1, 0);
      LDB(kt + 1, 1);                                   // B1(kt+1) [4]
    }
#pragma unroll
    for (int mi = 0; mi < 4; ++mi)
      aF[mi] = *(const bf16x8*)&As[p][0][(arow + 64 + mi * 16 + l15) * 32 + cA];
    asm volatile("s_waitcnt lgkmcnt(0)" ::: "memory");
    __builtin_amdgcn_s_barrier();
    __builtin_amdgcn_s_setprio(1);
#pragma unroll
    for (int mi = 0; mi < 4; ++mi)
#pragma unroll
      for (int ni = 0; ni < 4; ++ni)
        acc[4 + mi][ni] = mfma16(aF[mi], bF0[ni], acc[4 + mi][ni]);
    __builtin_amdgcn_s_setprio(0);
    __builtin_amdgcn_s_barrier();

    // ---- ph2: kk1, mi 0-3
    if (kt + 2 < NT) STA(kt + 2, 0);                  // A0(kt+2) [2]
#pragma unroll
    for (int mi = 0; mi < 4; ++mi)
      aF[mi] = *(const bf16x8*)&As[p][1][(arow + mi * 16 + l15) * 32 + cA];
#pragma unroll
    for (int ni = 0; ni < 4; ++ni)
      bF1[ni] = *(const bf16x8*)&Bs[p][1][(brow + ni * 16 + l15) * 32 + cA];
    __builtin_amdgcn_s_barrier();
    __builtin_amdgcn_s_setprio(1);
#pragma unroll
    for (int mi = 0; mi < 4; ++mi)
#pragma unroll
      for (int ni = 0; ni < 4; ++ni)
        acc[mi][ni] = mfma16(aF[mi], bF1[ni], acc[mi][ni]);
    __builtin_amdgcn_s_setprio(0);
    __builtin_amdgcn_s_barrier();

    // ---- ph3: kk1, mi 4-7 ; write B1(kt+1), load B0(kt+2)
    if (kt + 1 < NT) {
      if (kt + 2 < NT) asm volatile("s_waitcnt vmcnt(2)" ::: "memory");
      else             asm volatile("s_waitcnt vmcnt(0)" ::: "memory");
      WRB(p ^ 1, 1);
      if (kt + 2 < NT) LDB(kt + 2, 0);                // B0(kt+2) [4]
    }
#pragma unroll
    for (int mi = 0; mi < 4; ++mi)
      aF[mi] = *(const bf16x8*)&As[p][1][(arow + 64 + mi * 16 + l15) * 32 + cA];
    asm volatile("s_waitcnt lgkmcnt(0)" ::: "memory");
    __builtin_amdgcn_s_barrier();
    __builtin_amdgcn_s_setprio(1);
#pragma unroll
    for (int mi = 0; mi < 4; ++mi)
#pragma unroll
      for (int ni = 0; ni < 4; ++ni)
        acc[4 + mi][ni] = mfma16(aF[mi], bF1[ni], acc[4 + mi][ni]);
    __builtin_amdgcn_s_setprio(0);
    __builtin_amdgcn_s_barrier();
  }
#undef LDB
#undef WRB

#pragma unroll
  for (int mi = 0; mi < 8; ++mi)
#pragma unroll
    for (int ni = 0; ni < 4; ++ni) {
      int row0 = bm + wr * 128 + mi * 16 + l4 * 4;
      int col  = bn + wc * 64 + ni * 16 + l15;
#pragma unroll
      for (int r = 0; r < 4; r++) Cout[(size_t)(row0 + r) * N + col] = f2bf(acc[mi][ni][r]);
    }
}

// ---------------- GEMM 128x128 (proj) + fused f32 B-conversion ----------------
// m97 structure; B = Wd f32 reg-staged (load f32 -> cvt -> ds_write to the same
// slots gload_lds used: tid*8 / 2048+tid*8). Raw barriers + counted vmcnt:
// per iter: [bar] gloadA[2] ; vmcnt(2)->B(k0) regs ready; write; load B(k0+32)[4];
// vmcnt(4) -> A landed (B-next stays in flight across compute); lgkm(0); [bar].
__global__ __launch_bounds__(256, 2) void gemm_proj(
    const u16* __restrict__ A, const float* __restrict__ Bf, float* __restrict__ Cout,
    int M, int N, int K, const float* __restrict__ bias, const float* __restrict__ resid)
{
  int tid = threadIdx.x;
  int wv = tid >> 6, l = tid & 63, l15 = l & 15, l4 = l >> 4;
  int nbx = gridDim.x;
  int nwg = nbx * gridDim.y;
  int lin = blockIdx.y * nbx + blockIdx.x;
  int cpx = nwg >> 3;
  int swz = (lin & 7) * cpx + (lin >> 3);
  int bm = (swz / nbx) * 128, bn = (swz % nbx) * 128;

  __shared__ u16 As[128 * 32], Bs[128 * 32];
  f32x4 acc[4][4];
#pragma unroll
  for (int i = 0; i < 4; i++)
#pragma unroll
    for (int j = 0; j < 4; j++) acc[i][j] = f32x4{0.f, 0.f, 0.f, 0.f};

  int wm = (wv >> 1) * 64, wn = (wv & 1) * 64;
  const u16* gA = A + (size_t)(bm + (tid >> 2)) * K + (tid & 3) * 8;
  const float* gB = Bf + (size_t)(bn + (tid >> 2)) * K + (tid & 3) * 8;
  u16* ldsA = As + wv * 16 * 32;

  float4 s0, s1, s2, s3;
  s0 = *(const float4*)(gB);      s1 = *(const float4*)(gB + 4);
  s2 = *(const float4*)(gB + (size_t)64 * K); s3 = *(const float4*)(gB + (size_t)64 * K + 4);

  for (int k0 = 0; k0 < K; k0 += 32) {
    __builtin_amdgcn_s_barrier();            // prev tile's reads all consumed
    gload16(gA + k0, ldsA);
    gload16(gA + (size_t)64 * K + k0, ldsA + 64 * 32);
    asm volatile("s_waitcnt vmcnt(2)" ::: "memory");   // B(k0) regs ready
    *(bf16x8*)&As[0] = *(bf16x8*)&As[0];     // no-op placeholder removed below
    *(bf16x8*)&Bs[tid * 8]        = cvt8(s0, s1);
    *(bf16x8*)&Bs[2048 + tid * 8] = cvt8(s2, s3);
    bool more = (k0 + 32) < K;
    if (more) {
      s0 = *(const float4*)(gB + k0 + 32);      s1 = *(const float4*)(gB + k0 + 36);
      s2 = *(const float4*)(gB + (size_t)64 * K + k0 + 32);
      s3 = *(const float4*)(gB + (size_t)64 * K + k0 + 36);
      asm volatile("s_waitcnt vmcnt(4)" ::: "memory"); // A landed; B-next in flight
    } else {
      asm volatile("s_waitcnt vmcnt(0)" ::: "memory");
    }
    asm volatile("s_waitcnt lgkmcnt(0)" ::: "memory"); // B writes visible
    __builtin_amdgcn_s_barrier();
    bf16x8 af[4], bfr[4];
#pragma unroll
    for (int i = 0; i < 4; i++) af[i] = *(const bf16x8*)&As[(wm + i * 16 + l15) * 32 + l4 * 8];
#pragma unroll
    for (int i = 0; i < 4; i++) bfr[i] = *(const bf16x8*)&Bs[(wn + i * 16 + l15) * 32 + l4 * 8];
#pragma unroll
    for (int mi = 0; mi < 4; mi++)
#pragma unroll
      for (int ni = 0; ni < 4; ni++) acc[mi][ni] = mfma16(af[mi], bfr[ni], acc[mi][ni]);
  }

#pragma unroll
  for (int mi = 0; mi < 4; mi++)
#pragma unroll
    for (int ni = 0; ni < 4; ni++) {
      int row0 = bm + wm + mi * 16 + l4 * 4;
      int col  = bn + wn + ni * 16 + l15;
      float b = bias[col];
#pragma unroll
      for (int r = 0; r < 4; r++) {
        size_t idx = (size_t)(row0 + r) * N + col;
        Cout[idx] = acc[mi][ni][r] + b + resid[idx];
      }
    }
}

// ---------------- Flash attention v4 (causal, LDS-staged K/V) -----------------
__global__ __launch_bounds__(512, 4) void attn_kernel(
    const u16* __restrict__ Qr, const u16* __restrict__ Kr,
    const u16* __restrict__ Vt, u16* __restrict__ ctx)
{
  int lin = blockIdx.x;
  int h  = lin & 31;               // same head -> same XCD (lin%8 == h%8 both halves)
  int qx = (lin < 256) ? (15 - (lin >> 5)) : ((lin - 256) >> 5);
  int q0 = qx * 128;
  int tid = threadIdx.x;
  int w = tid >> 6, l = tid & 63, l15 = l & 15, l4 = l >> 4;
  int qb = q0 + w * 16;

  __shared__ u16 Ks[64][164];      // 328B row stride: <=2-way on frag reads
  __shared__ u16 Vs[160][68];      // 136B row stride: conflict-free reads
  __shared__ u16 Plds[8][16][68];  // per-wave P tile

  const u16* Qh = Qr + (size_t)h * S_LEN * HDIM;
  const u16* Kh = Kr + (size_t)h * S_LEN * HDIM;
  const u16* Vh = Vt + (size_t)h * HDIM * S_LEN;

  bf16x8 aQ[5];
#pragma unroll
  for (int kc = 0; kc < 5; kc++)
    aQ[kc] = *(const bf16x8*)&Qh[(size_t)(qb + l15) * HDIM + kc * 32 + l4 * 8];

  f32x4 accO[10];
#pragma unroll
  for (int dt = 0; dt < 10; dt++) accO[dt] = f32x4{0.f, 0.f, 0.f, 0.f};
  float mrun[4], lrun[4];
#pragma unroll
  for (int r = 0; r < 4; r++) { mrun[r] = -1e30f; lrun[r] = 0.f; }

  const float c2 = 0.07905694150420949f * 1.44269504088896f;  // 1/sqrt(160)*log2(e)
  int Tend = 2 * qx + 2;           // k tiles cover k <= q0+127

  {
    uint4 rg[5];
#pragma unroll
    for (int i = 0; i < 5; i++) {
      int u = tid + 512 * i;
      if (u < 1280) { int row = u / 20, c = u % 20;
        rg[i] = *(const uint4*)&Kh[(size_t)row * HDIM + c * 8]; }
      else { int v = u - 1280; int row = v >> 3, c = v & 7;
        rg[i] = *(const uint4*)&Vh[(size_t)row * S_LEN + c * 8]; }
    }
#pragma unroll
    for (int i = 0; i < 5; i++) {
      int u = tid + 512 * i;
      if (u < 1280) { int row = u / 20, c = u % 20; *(uint4*)&Ks[row][c * 8] = rg[i]; }
      else { int v = u - 1280; int row = v >> 3, c = v & 7; *(uint4*)&Vs[row][c * 8] = rg[i]; }
    }
  }
  __syncthreads();

  for (int t = 0; t < Tend; ++t) {
    int k0 = t * 64;
    bool more = (t + 1 < Tend);
    uint4 rg[5];
    if (more) {                     // issue next-tile loads early (T14)
      int k1 = k0 + 64;
#pragma unroll
      for (int i = 0; i < 5; i++) {
        int u = tid + 512 * i;
        if (u < 1280) { int row = u / 20, c = u % 20;
          rg[i] = *(const uint4*)&Kh[(size_t)(k1 + row) * HDIM + c * 8]; }
        else { int v = u - 1280; int row = v >> 3, c = v & 7;
          rg[i] = *(const uint4*)&Vh[(size_t)row * S_LEN + k1 + c * 8]; }
      }
    }

    if (k0 <= qb + 15) {            // wave-active (causal tile skip)
      f32x4 s_[4];
#pragma unroll
      for (int nt = 0; nt < 4; nt++) s_[nt] = f32x4{0.f, 0.f, 0.f, 0.f};

#pragma unroll
      for (int kc = 0; kc < 5; kc++) {
        bf16x8 bK[4];
#pragma unroll
        for (int nt = 0; nt < 4; nt++)
          bK[nt] = *(const bf16x8*)&Ks[nt * 16 + l15][kc * 32 + l4 * 8];
        __builtin_amdgcn_s_setprio(1);
#pragma unroll
        for (int nt = 0; nt < 4; nt++) s_[nt] = mfma16(aQ[kc], bK[nt], s_[nt]);
        __builtin_amdgcn_s_setprio(0);
      }

      if (k0 + 63 > qb) {           // diagonal-region mask
#pragma unroll
        for (int nt = 0; nt < 4; nt++)
#pragma unroll
          for (int r = 0; r < 4; r++) {
            int kk = k0 + nt * 16 + l15;
            int qq = qb + l4 * 4 + r;
            if (kk > qq) s_[nt][r] = -1e30f;
          }
      }

      float sf[4];
#pragma unroll
      for (int r = 0; r < 4; r++) {
        float v = fmaxf(fmaxf(s_[0][r], s_[1][r]), fmaxf(s_[2][r], s_[3][r]));
#pragma unroll
        for (int m = 1; m <= 8; m <<= 1) v = fmaxf(v, __shfl_xor(v, m));
        float mnew = fmaxf(mrun[r], v);
        sf[r] = exp2f((mrun[r] - mnew) * c2);
        mrun[r] = mnew;
      }
      float rsum[4] = {0.f, 0.f, 0.f, 0.f};
#pragma unroll
      for (int nt = 0; nt < 4; nt++)
#pragma unroll
        for (int r = 0; r < 4; r++) {
          float p = exp2f((s_[nt][r] - mrun[r]) * c2);
          s_[nt][r] = p;
          rsum[r] += p;
        }
#pragma unroll
      for (int r = 0; r < 4; r++) {
        float v = rsum[r];
#pragma unroll
        for (int m = 1; m <= 8; m <<= 1) v += __shfl_xor(v, m);
        lrun[r] = lrun[r] * sf[r] + v;
      }
#pragma unroll
      for (int dt = 0; dt < 10; dt++)
#pragma unroll
        for (int r = 0; r < 4; r++) accO[dt][r] *= sf[r];
#pragma unroll
      for (int nt = 0; nt < 4; nt++)
#pragma unroll
        for (int r = 0; r < 4; r++)
          Plds[w][l4 * 4 + r][nt * 16 + l15] = f2bf(s_[nt][r]);

      // PV: A = P (wave-local LDS), B = V rows (block LDS)
#pragma unroll
      for (int kc = 0; kc < 2; kc++) {
        bf16x8 aP = *(const bf16x8*)&Plds[w][l15][kc * 32 + l4 * 8];
        bf16x8 bV[10];
#pragma unroll
        for (int dt = 0; dt < 10; dt++)
          bV[dt] = *(const bf16x8*)&Vs[dt * 16 + l15][kc * 32 + l4 * 8];
        __builtin_amdgcn_s_setprio(1);
#pragma unroll
        for (int dt = 0; dt < 10; dt++)
          accO[dt] = mfma16(aP, bV[dt], accO[dt]);
        __builtin_amdgcn_s_setprio(0);
      }
    }

    __builtin_amdgcn_s_barrier();
    if (more) {
#pragma unroll
      for (int i = 0; i < 5; i++) {
        int u = tid + 512 * i;
        if (u < 1280) { int row = u / 20, c = u % 20; *(uint4*)&Ks[row][c * 8] = rg[i]; }
        else { int v = u - 1280; int row = v >> 3, c = v & 7; *(uint4*)&Vs[row][c * 8] = rg[i]; }
      }
      asm volatile("s_waitcnt lgkmcnt(0)" ::: "memory");  // writes visible to other waves
    }
    __builtin_amdgcn_s_barrier();
  }

  float inv[4];
#pragma unroll
  for (int r = 0; r < 4; r++) inv[r] = 1.0f / lrun[r];
#pragma unroll
  for (int dt = 0; dt < 10; dt++)
#pragma unroll
    for (int r = 0; r < 4; r++) {
      int q = qb + l4 * 4 + r;
      ctx[(size_t)q * HID + h * HDIM + dt * 16 + l15] = f2bf(accO[dt][r] * inv[r]);
    }
}

// -----------------------------------------------------------------------------
extern "C" void kernel_launch(void* const* d_in, const int* in_sizes, int n_in,
                              void* d_out, int out_size, void* d_ws, size_t ws_size,
                              hipStream_t stream) {
  const float* hs    = (const float*)d_in[0];
  const float* resid = (const float*)d_in[1];
  // d_in[2] = attention_mask (causal triu) — implied by kernel, ignored
  const float* Wq  = (const float*)d_in[3];
  const float* Wkv = (const float*)d_in[4];
  const float* Wd  = (const float*)d_in[5];
  const float* bd  = (const float*)d_in[6];
  float* out = (float*)d_out;

  char* ws = (char*)d_ws;
  const size_t SH = (size_t)S_LEN * HID;          // 10,485,760
  u16* Xb     = (u16*)(ws);                        size_t off = SH * 2;
  u16* QKVraw = (u16*)(ws + off);                  off += (size_t)S_LEN * NQKV * 2;  // [2048][15360]
  u16* Qr     = (u16*)(ws + off);                  off += SH * 2;
  u16* Kr     = (u16*)(ws + off);                  off += SH * 2;
  u16* Vt     = (u16*)(ws + off);                  off += SH * 2;
  u16* ctx    = (u16*)(ws + off);                  off += SH * 2;
  float2* tab = (float2*)(ws + off);               off += (size_t)S_LEN * 80 * 8;

  // 1) convert hs to bf16 (weights are consumed as f32 inside the GEMMs now)
  cvt_bf16_kernel<<<(int)(SH / 8 / 256), 256, 0, stream>>>(hs, Xb, (int)(SH / 8));

  // 2) RoPE table
  rope_table_kernel<<<64, 256, 0, stream>>>(tab);

  // 3) fused QKV projection: [2048,15360] = Xb @ [Wq|Wkv]^T  (B from f32)
  gemm256_qkv<<<dim3(NQKV / 256, S_LEN / 256), 512, 0, stream>>>(
      Xb, Wq, Wkv, QKVraw, S_LEN, NQKV, HID);

  // 4) RoPE + relayout; V transpose (all reading fused QKVraw)
  rope_apply_kernel<<<S_LEN * NHEAD * 80 / 256, 256, 0, stream>>>(QKVraw, tab, Qr, HDIM, NQKV);
  rope_apply_kernel<<<S_LEN * NHEAD * 80 / 256, 256, 0, stream>>>(QKVraw + HID, tab, Kr, 2 * HDIM, NQKV);
  vtrans_kernel<<<dim3(S_LEN / 64, NHEAD), 256, 0, stream>>>(QKVraw + HID + HDIM, Vt, NQKV);

  // 5) attention (balanced pairing, raw barriers, 128 q-rows per block)
  attn_kernel<<<512, 512, 0, stream>>>(Qr, Kr, Vt, ctx);

  // 6) output projection + bias + residual (B = Wd f32, fused cvt)
  gemm_proj<<<dim3(HID / 128, S_LEN / 128), 256, 0, stream>>>(
      ctx, Wd, out, S_LEN, HID, HID, bd, resid);
}

// Round 10
// 971.675 us; speedup vs baseline: 1.0909x; 1.0909x over previous
//
#include <hip/hip_runtime.h>
#include <cmath>

typedef unsigned short u16;
typedef unsigned int   u32;

using bf16x8 = __attribute__((ext_vector_type(8))) short;   // 8 bf16 in 4 VGPRs
using f32x4  = __attribute__((ext_vector_type(4))) float;

#define S_LEN 2048
#define NHEAD 32
#define HDIM  160
#define HID   5120   // NHEAD*HDIM
#define NQKV  15360  // HID + 2*HID

__device__ __forceinline__ f32x4 mfma16(bf16x8 a, bf16x8 b, f32x4 c) {
  return __builtin_amdgcn_mfma_f32_16x16x32_bf16(a, b, c, 0, 0, 0);
}

__device__ __forceinline__ u16 f2bf(float f) {          // RNE f32->bf16
  u32 u = __builtin_bit_cast(u32, f);
  u += 0x7FFFu + ((u >> 16) & 1u);
  return (u16)(u >> 16);
}
__device__ __forceinline__ float bf2f(u16 h) {
  u32 u = ((u32)h) << 16;
  return __builtin_bit_cast(float, u);
}

// async global->LDS, 16B per lane; LDS dest is wave-uniform base + lane*16
__device__ __forceinline__ void gload16(const void* g, void* l) {
  __builtin_amdgcn_global_load_lds((const __attribute__((address_space(1))) void*)g,
                                   (__attribute__((address_space(3))) void*)l, 16, 0, 0);
}

// ---------------- fused f32 -> bf16 convert for hs + Wq + Wkv + Wd ------------
// One launch, grid-stride over 4 segments (8 f32 per item). Memory-bound; same
// traffic as 4 kernels but one ramp/tail. Segment boundaries are item-exact.
__global__ void cvt_all_kernel(const float* __restrict__ hs, const float* __restrict__ Wq,
                               const float* __restrict__ Wkv, const float* __restrict__ Wd,
                               u16* __restrict__ Xb, u16* __restrict__ Wqkvb,
                               u16* __restrict__ Wdb) {
  const int n_hs = S_LEN * HID / 8;          // 1,310,720
  const int n_q  = HID * HID / 8;            // 3,276,800
  const int n_kv = 2 * HID * HID / 8;        // 6,553,600
  const int n_d  = HID * HID / 8;            // 3,276,800
  const int total = n_hs + n_q + n_kv + n_d; // 14,417,920
  for (int i = blockIdx.x * 256 + threadIdx.x; i < total; i += gridDim.x * 256) {
    const float* src; u16* dst; int j = i;
    if (j < n_hs)                { src = hs;  dst = Xb; }
    else if ((j -= n_hs) < n_q)  { src = Wq;  dst = Wqkvb; }
    else if ((j -= n_q) < n_kv)  { src = Wkv; dst = Wqkvb + (size_t)HID * HID; }
    else { j -= n_kv;              src = Wd;  dst = Wdb; }
    float4 a = ((const float4*)src)[(size_t)j * 2];
    float4 b = ((const float4*)src)[(size_t)j * 2 + 1];
    uint4 o;
    o.x = (u32)f2bf(a.x) | ((u32)f2bf(a.y) << 16);
    o.y = (u32)f2bf(a.z) | ((u32)f2bf(a.w) << 16);
    o.z = (u32)f2bf(b.x) | ((u32)f2bf(b.y) << 16);
    o.w = (u32)f2bf(b.z) | ((u32)f2bf(b.w) << 16);
    ((uint4*)dst)[j] = o;
  }
}

// ---------------- RoPE table: tab[s][j] = (cos, sin), j<80 -------------------
// eff=8192 -> mscale=1.0, ntk_alpha=3, base=10000*3^(160/158).
__global__ void rope_table_kernel(float2* __restrict__ tab) {
  __shared__ double invf_s[80];
  int tid = threadIdx.x;
  if (tid < 80) {
    double base = 10000.0 * pow(3.0, 160.0 / 158.0);
    invf_s[tid] = pow(base, -((double)(2 * tid)) / 160.0);
  }
  __syncthreads();
  for (int i = blockIdx.x * 256 + tid; i < S_LEN * 80; i += gridDim.x * 256) {
    int s = i / 80, j = i % 80;
    double ang = fmod((double)s * invf_s[j], 6.283185307179586476925287);
    float a = (float)ang;
    tab[i] = make_float2(cosf(a), sinf(a));
  }
}

// ---------------- RoPE apply (Q and K in one launch) + head-major relayout ----
// First half of the grid: Q slice (headStride=160); second half: K slice
// (headStride=320, src offset +HID). Boundary is block-aligned (no divergence).
__global__ void rope_apply2_kernel(const u16* __restrict__ qkv, const float2* __restrict__ tab,
                                   u16* __restrict__ Qr, u16* __restrict__ Kr) {
  const int n = S_LEN * NHEAD * 80;                 // per-slice dword-pairs
  int i = blockIdx.x * 256 + threadIdx.x;
  bool isK = i >= n;
  if (isK) i -= n;
  const u16* src = qkv + (isK ? HID : 0);
  int headStride = isK ? 2 * HDIM : HDIM;
  u16* dst = isK ? Kr : Qr;

  int dp = i % 80; int sh = i / 80; int h = sh % NHEAD; int s = sh / NHEAD;
  int d = 2 * dp;
  const u16* row = src + (size_t)s * NQKV + h * headStride;
  u32 q01 = *(const u32*)&row[d];
  u32 p01 = *(const u32*)&row[d < 80 ? d + 80 : d - 80];
  int j = (d < 80) ? d : d - 80;
  float2 cs0 = tab[s * 80 + j];
  float2 cs1 = tab[s * 80 + j + 1];
  float q0 = bf2f((u16)(q01 & 0xffff)), q1 = bf2f((u16)(q01 >> 16));
  float p0 = bf2f((u16)(p01 & 0xffff)), p1 = bf2f((u16)(p01 >> 16));
  float sgn = (d < 80) ? -1.f : 1.f;                // out = x*cos + rot_half(x)*sin
  float o0 = q0 * cs0.x + sgn * p0 * cs0.y;
  float o1 = q1 * cs1.x + sgn * p1 * cs1.y;
  u32 o = (u32)f2bf(o0) | ((u32)f2bf(o1) << 16);
  *(u32*)&dst[((size_t)h * S_LEN + s) * HDIM + d] = o;
}

// ---------------- V transpose: v-slice of fused QKV -> Vt[h][d][s] -----------
__global__ void vtrans_kernel(const u16* __restrict__ src, u16* __restrict__ Vt, int rowStride) {
  __shared__ u16 T[HDIM][72];                       // pad 64->72 (2-way max on reads)
  int h = blockIdx.y; int s0 = blockIdx.x * 64; int tid = threadIdx.x;
  for (int i = tid; i < 64 * 80; i += 256) {
    int s = i / 80, dp = i % 80;
    u32 v = *(const u32*)&src[(size_t)(s0 + s) * rowStride + h * 320 + 2 * dp];
    T[2 * dp][s]     = (u16)(v & 0xffff);
    T[2 * dp + 1][s] = (u16)(v >> 16);
  }
  __syncthreads();
  for (int i = tid; i < HDIM * 32; i += 256) {
    int d = i / 32, sp = i % 32;
    u32 v = (u32)T[d][2 * sp] | ((u32)T[d][2 * sp + 1] << 16);
    *(u32*)&Vt[((size_t)h * HDIM + d) * S_LEN + s0 + 2 * sp] = v;
  }
}

// ---------------- GEMM 256x256, m201-faithful 8-phase (T2+T3+T4+T5) -----------
// R8-measured 828 TF (MfmaUtil 35.4%, 0 bank conflicts). bf16 A and B via
// global_load_lds (bf16 B panel is L3-resident across row-tile re-reads; R9
// proved f32-B fusion doubles HBM traffic and loses). kk-major staging units,
// stream [B0,A0,B1,A1] offset so ph0 issues kt+1's A1, ph1-3 issue kt+2's
// B0/A0/B1; ONE vmcnt(6) per K-tile at ph3. st_16x32 swizzle both sides.
template<int EPI>
__global__ __launch_bounds__(512, 2) void gemm256(
    const u16* __restrict__ A, const u16* __restrict__ Bm, void* __restrict__ Cout,
    int M, int N, int K, const float* __restrict__ bias, const float* __restrict__ resid)
{
  __shared__ u16 As[2][2][8192];   // [dbuf][kk][256*32]  64 KB
  __shared__ u16 Bs[2][2][8192];   // 64 KB
  int tid = threadIdx.x;
  int w = tid >> 6, l = tid & 63, l15 = l & 15, l4 = l >> 4;
  int wr = w >> 2, wc = w & 3;

  // XCD chunked swizzle (nwg % 8 == 0 guaranteed by launch)
  int nbx = gridDim.x;
  int nwg = nbx * gridDim.y;
  int lin = blockIdx.y * nbx + blockIdx.x;
  int cpx = nwg >> 3;
  int swz = (lin & 7) * cpx + (lin >> 3);
  int bm = (swz / nbx) * 256, bn = (swz % nbx) * 256;

  int srow = tid >> 2;                                  // 0..127
  int scol = ((tid & 3) * 8) ^ ((srow & 8) ? 16 : 0);   // pre-swizzled source col
  const u16* gAr = A  + (size_t)(bm + srow) * K + scol;
  const u16* gBr = Bm + (size_t)(bn + srow) * K + scol;
  int w512 = w * 512;                                   // wave-uniform dest (elems)

  f32x4 acc[8][4];
#pragma unroll
  for (int i = 0; i < 8; i++)
#pragma unroll
    for (int j = 0; j < 4; j++) acc[i][j] = f32x4{0.f, 0.f, 0.f, 0.f};

  int cA = (l4 * 8) ^ ((l15 & 8) ? 16 : 0);             // read-side swizzle (const)
  const int NT = K >> 6;
  int arow = wr * 128;                                  // wave A row base
  int brow = (wc >> 1) * 128 + (wc & 1) * 64;           // wave B row base

  auto STA = [&](int kt, int kk) { int p = kt & 1, ko = (kt << 6) + (kk << 5);
    gload16(gAr + ko, &As[p][kk][w512]);
    gload16(gAr + (size_t)128 * K + ko, &As[p][kk][4096 + w512]); };
  auto STB = [&](int kt, int kk) { int p = kt & 1, ko = (kt << 6) + (kk << 5);
    gload16(gBr + ko, &Bs[p][kk][w512]);
    gload16(gBr + (size_t)128 * K + ko, &Bs[p][kk][4096 + w512]); };

  // prologue: K0 complete + K1's first 3 units (stream order [B0,A0,B1,A1])
  STB(0, 0); STA(0, 0); STB(0, 1); STA(0, 1);
  if (NT > 1) { STB(1, 0); STA(1, 0); STB(1, 1); }
  asm volatile("s_waitcnt vmcnt(6)" ::: "memory");      // K0's 4 units landed
  __builtin_amdgcn_s_barrier();

  for (int kt = 0; kt < NT; ++kt) {
    int p = kt & 1;
    bf16x8 aF[4], bF0[4], bF1[4];

    // ---- ph0: kk0, mi 0-3 (8 ds_reads)
    if (kt + 1 < NT) STA(kt + 1, 1);                    // kt+1's A_kk1 (last unit)
#pragma unroll
    for (int mi = 0; mi < 4; ++mi)
      aF[mi] = *(const bf16x8*)&As[p][0][(arow + mi * 16 + l15) * 32 + cA];
#pragma unroll
    for (int ni = 0; ni < 4; ++ni)
      bF0[ni] = *(const bf16x8*)&Bs[p][0][(brow + ni * 16 + l15) * 32 + cA];
    __builtin_amdgcn_s_barrier();
    __builtin_amdgcn_s_setprio(1);
#pragma unroll
    for (int mi = 0; mi < 4; ++mi)
#pragma unroll
      for (int ni = 0; ni < 4; ++ni)
        acc[mi][ni] = mfma16(aF[mi], bF0[ni], acc[mi][ni]);
    __builtin_amdgcn_s_setprio(0);
    __builtin_amdgcn_s_barrier();

    // ---- ph1: kk0, mi 4-7 (4 ds_reads; bF0 reused from regs)
    if (kt + 2 < NT) STB(kt + 2, 0);                    // B_kk0(kt) dead after ph0
#pragma unroll
    for (int mi = 0; mi < 4; ++mi)
      aF[mi] = *(const bf16x8*)&As[p][0][(arow + 64 + mi * 16 + l15) * 32 + cA];
    __builtin_amdgcn_s_barrier();
    __builtin_amdgcn_s_setprio(1);
#pragma unroll
    for (int mi = 0; mi < 4; ++mi)
#pragma unroll
      for (int ni = 0; ni < 4; ++ni)
        acc[4 + mi][ni] = mfma16(aF[mi], bF0[ni], acc[4 + mi][ni]);
    __builtin_amdgcn_s_setprio(0);
    __builtin_amdgcn_s_barrier();

    // ---- ph2: kk1, mi 0-3 (8 ds_reads)
    if (kt + 2 < NT) STA(kt + 2, 0);                    // A_kk0(kt) dead after ph1
#pragma unroll
    for (int mi = 0; mi < 4; ++mi)
      aF[mi] = *(const bf16x8*)&As[p][1][(arow + mi * 16 + l15) * 32 + cA];
#pragma unroll
    for (int ni = 0; ni < 4; ++ni)
      bF1[ni] = *(const bf16x8*)&Bs[p][1][(brow + ni * 16 + l15) * 32 + cA];
    __builtin_amdgcn_s_barrier();
    __builtin_amdgcn_s_setprio(1);
#pragma unroll
    for (int mi = 0; mi < 4; ++mi)
#pragma unroll
      for (int ni = 0; ni < 4; ++ni)
        acc[mi][ni] = mfma16(aF[mi], bF1[ni], acc[mi][ni]);
    __builtin_amdgcn_s_setprio(0);
    __builtin_amdgcn_s_barrier();

    // ---- ph3: kk1, mi 4-7 (4 ds_reads) + the ONE counted wait per K-tile
    if (kt + 2 < NT) STB(kt + 2, 1);                    // B_kk1(kt) dead after ph2
#pragma unroll
    for (int mi = 0; mi < 4; ++mi)
      aF[mi] = *(const bf16x8*)&As[p][1][(arow + 64 + mi * 16 + l15) * 32 + cA];
    __builtin_amdgcn_s_barrier();
    __builtin_amdgcn_s_setprio(1);
#pragma unroll
    for (int mi = 0; mi < 4; ++mi)
#pragma unroll
      for (int ni = 0; ni < 4; ++ni)
        acc[4 + mi][ni] = mfma16(aF[mi], bF1[ni], acc[4 + mi][ni]);
    __builtin_amdgcn_s_setprio(0);
    if (kt + 2 < NT)      asm volatile("s_waitcnt vmcnt(6)" ::: "memory");
    else if (kt + 1 < NT) asm volatile("s_waitcnt vmcnt(0)" ::: "memory");
    __builtin_amdgcn_s_barrier();
  }

#pragma unroll
  for (int mi = 0; mi < 8; ++mi)
#pragma unroll
    for (int ni = 0; ni < 4; ++ni) {
      int row0 = bm + wr * 128 + mi * 16 + l4 * 4;
      int col  = bn + wc * 64 + ni * 16 + l15;
      if (EPI == 0) {
        u16* C = (u16*)Cout;
#pragma unroll
        for (int r = 0; r < 4; r++) C[(size_t)(row0 + r) * N + col] = f2bf(acc[mi][ni][r]);
      } else {
        float* C = (float*)Cout;
        float b = bias[col];
#pragma unroll
        for (int r = 0; r < 4; r++) {
          size_t idx = (size_t)(row0 + r) * N + col;
          C[idx] = acc[mi][ni][r] + b + resid[idx];
        }
      }
    }
}

// ---------------- GEMM 128x128 (m97 structure; proj only — 640 blocks fill GPU)
template<int EPI>
__global__ __launch_bounds__(256, 2) void gemm_bt(
    const u16* __restrict__ A, const u16* __restrict__ Bm, void* __restrict__ Cout,
    int M, int N, int K, const float* __restrict__ bias, const float* __restrict__ resid)
{
  int tid = threadIdx.x;
  int wv = tid >> 6, l = tid & 63, l15 = l & 15, l4 = l >> 4;
  int nbx = gridDim.x;
  int nwg = nbx * gridDim.y;
  int lin = blockIdx.y * nbx + blockIdx.x;
  int cpx = nwg >> 3;
  int swz = (lin & 7) * cpx + (lin >> 3);
  int bm = (swz / nbx) * 128, bn = (swz % nbx) * 128;

  __shared__ u16 As[128 * 32], Bs[128 * 32];
  f32x4 acc[4][4];
#pragma unroll
  for (int i = 0; i < 4; i++)
#pragma unroll
    for (int j = 0; j < 4; j++) acc[i][j] = f32x4{0.f, 0.f, 0.f, 0.f};

  int wm = (wv >> 1) * 64, wn = (wv & 1) * 64;
  const u16* gA = A + (size_t)(bm + (tid >> 2)) * K + (tid & 3) * 8;
  const u16* gB = Bm + (size_t)(bn + (tid >> 2)) * K + (tid & 3) * 8;
  u16* ldsA = As + wv * 16 * 32;
  u16* ldsB = Bs + wv * 16 * 32;

  for (int k0 = 0; k0 < K; k0 += 32) {
    __syncthreads();
    gload16(gA + k0, ldsA);
    gload16(gA + (size_t)64 * K + k0, ldsA + 64 * 32);
    gload16(gB + k0, ldsB);
    gload16(gB + (size_t)64 * K + k0, ldsB + 64 * 32);
    __syncthreads();
    bf16x8 af[4], bfr[4];
#pragma unroll
    for (int i = 0; i < 4; i++) af[i] = *(const bf16x8*)&As[(wm + i * 16 + l15) * 32 + l4 * 8];
#pragma unroll
    for (int i = 0; i < 4; i++) bfr[i] = *(const bf16x8*)&Bs[(wn + i * 16 + l15) * 32 + l4 * 8];
#pragma unroll
    for (int mi = 0; mi < 4; mi++)
#pragma unroll
      for (int ni = 0; ni < 4; ni++) acc[mi][ni] = mfma16(af[mi], bfr[ni], acc[mi][ni]);
  }

#pragma unroll
  for (int mi = 0; mi < 4; mi++)
#pragma unroll
    for (int ni = 0; ni < 4; ni++) {
      int row0 = bm + wm + mi * 16 + l4 * 4;
      int col  = bn + wn + ni * 16 + l15;
      if (EPI == 0) {
        u16* C = (u16*)Cout;
#pragma unroll
        for (int r = 0; r < 4; r++) C[(size_t)(row0 + r) * N + col] = f2bf(acc[mi][ni][r]);
      } else {
        float* C = (float*)Cout;
        float b = bias[col];
#pragma unroll
        for (int r = 0; r < 4; r++) {
          size_t idx = (size_t)(row0 + r) * N + col;
          C[idx] = acc[mi][ni][r] + b + resid[idx];
        }
      }
    }
}

// ---------------- Flash attention v4 (causal, LDS-staged K/V) -----------------
__global__ __launch_bounds__(512, 4) void attn_kernel(
    const u16* __restrict__ Qr, const u16* __restrict__ Kr,
    const u16* __restrict__ Vt, u16* __restrict__ ctx)
{
  int lin = blockIdx.x;
  int h  = lin & 31;               // same head -> same XCD (lin%8 == h%8 both halves)
  int qx = (lin < 256) ? (15 - (lin >> 5)) : ((lin - 256) >> 5);
  int q0 = qx * 128;
  int tid = threadIdx.x;
  int w = tid >> 6, l = tid & 63, l15 = l & 15, l4 = l >> 4;
  int qb = q0 + w * 16;

  __shared__ u16 Ks[64][164];      // 328B row stride: <=2-way on frag reads
  __shared__ u16 Vs[160][68];      // 136B row stride: conflict-free reads
  __shared__ u16 Plds[8][16][68];  // per-wave P tile

  const u16* Qh = Qr + (size_t)h * S_LEN * HDIM;
  const u16* Kh = Kr + (size_t)h * S_LEN * HDIM;
  const u16* Vh = Vt + (size_t)h * HDIM * S_LEN;

  bf16x8 aQ[5];
#pragma unroll
  for (int kc = 0; kc < 5; kc++)
    aQ[kc] = *(const bf16x8*)&Qh[(size_t)(qb + l15) * HDIM + kc * 32 + l4 * 8];

  f32x4 accO[10];
#pragma unroll
  for (int dt = 0; dt < 10; dt++) accO[dt] = f32x4{0.f, 0.f, 0.f, 0.f};
  float mrun[4], lrun[4];
#pragma unroll
  for (int r = 0; r < 4; r++) { mrun[r] = -1e30f; lrun[r] = 0.f; }

  const float c2 = 0.07905694150420949f * 1.44269504088896f;  // 1/sqrt(160)*log2(e)
  int Tend = 2 * qx + 2;           // k tiles cover k <= q0+127

  {
    uint4 rg[5];
#pragma unroll
    for (int i = 0; i < 5; i++) {
      int u = tid + 512 * i;
      if (u < 1280) { int row = u / 20, c = u % 20;
        rg[i] = *(const uint4*)&Kh[(size_t)row * HDIM + c * 8]; }
      else { int v = u - 1280; int row = v >> 3, c = v & 7;
        rg[i] = *(const uint4*)&Vh[(size_t)row * S_LEN + c * 8]; }
    }
#pragma unroll
    for (int i = 0; i < 5; i++) {
      int u = tid + 512 * i;
      if (u < 1280) { int row = u / 20, c = u % 20; *(uint4*)&Ks[row][c * 8] = rg[i]; }
      else { int v = u - 1280; int row = v >> 3, c = v & 7; *(uint4*)&Vs[row][c * 8] = rg[i]; }
    }
  }
  __syncthreads();

  for (int t = 0; t < Tend; ++t) {
    int k0 = t * 64;
    bool more = (t + 1 < Tend);
    uint4 rg[5];
    if (more) {                     // issue next-tile loads early (T14)
      int k1 = k0 + 64;
#pragma unroll
      for (int i = 0; i < 5; i++) {
        int u = tid + 512 * i;
        if (u < 1280) { int row = u / 20, c = u % 20;
          rg[i] = *(const uint4*)&Kh[(size_t)(k1 + row) * HDIM + c * 8]; }
        else { int v = u - 1280; int row = v >> 3, c = v & 7;
          rg[i] = *(const uint4*)&Vh[(size_t)row * S_LEN + k1 + c * 8]; }
      }
    }

    if (k0 <= qb + 15) {            // wave-active (causal tile skip)
      f32x4 s_[4];
#pragma unroll
      for (int nt = 0; nt < 4; nt++) s_[nt] = f32x4{0.f, 0.f, 0.f, 0.f};

#pragma unroll
      for (int kc = 0; kc < 5; kc++) {
        bf16x8 bK[4];
#pragma unroll
        for (int nt = 0; nt < 4; nt++)
          bK[nt] = *(const bf16x8*)&Ks[nt * 16 + l15][kc * 32 + l4 * 8];
        __builtin_amdgcn_s_setprio(1);
#pragma unroll
        for (int nt = 0; nt < 4; nt++) s_[nt] = mfma16(aQ[kc], bK[nt], s_[nt]);
        __builtin_amdgcn_s_setprio(0);
      }

      if (k0 + 63 > qb) {           // diagonal-region mask
#pragma unroll
        for (int nt = 0; nt < 4; nt++)
#pragma unroll
          for (int r = 0; r < 4; r++) {
            int kk = k0 + nt * 16 + l15;
            int qq = qb + l4 * 4 + r;
            if (kk > qq) s_[nt][r] = -1e30f;
          }
      }

      float sf[4];
#pragma unroll
      for (int r = 0; r < 4; r++) {
        float v = fmaxf(fmaxf(s_[0][r], s_[1][r]), fmaxf(s_[2][r], s_[3][r]));
#pragma unroll
        for (int m = 1; m <= 8; m <<= 1) v = fmaxf(v, __shfl_xor(v, m));
        float mnew = fmaxf(mrun[r], v);
        sf[r] = exp2f((mrun[r] - mnew) * c2);
        mrun[r] = mnew;
      }
      float rsum[4] = {0.f, 0.f, 0.f, 0.f};
#pragma unroll
      for (int nt = 0; nt < 4; nt++)
#pragma unroll
        for (int r = 0; r < 4; r++) {
          float p = exp2f((s_[nt][r] - mrun[r]) * c2);
          s_[nt][r] = p;
          rsum[r] += p;
        }
#pragma unroll
      for (int r = 0; r < 4; r++) {
        float v = rsum[r];
#pragma unroll
        for (int m = 1; m <= 8; m <<= 1) v += __shfl_xor(v, m);
        lrun[r] = lrun[r] * sf[r] + v;
      }
#pragma unroll
      for (int dt = 0; dt < 10; dt++)
#pragma unroll
        for (int r = 0; r < 4; r++) accO[dt][r] *= sf[r];
#pragma unroll
      for (int nt = 0; nt < 4; nt++)
#pragma unroll
        for (int r = 0; r < 4; r++)
          Plds[w][l4 * 4 + r][nt * 16 + l15] = f2bf(s_[nt][r]);

      // PV: A = P (wave-local LDS), B = V rows (block LDS)
#pragma unroll
      for (int kc = 0; kc < 2; kc++) {
        bf16x8 aP = *(const bf16x8*)&Plds[w][l15][kc * 32 + l4 * 8];
        bf16x8 bV[10];
#pragma unroll
        for (int dt = 0; dt < 10; dt++)
          bV[dt] = *(const bf16x8*)&Vs[dt * 16 + l15][kc * 32 + l4 * 8];
        __builtin_amdgcn_s_setprio(1);
#pragma unroll
        for (int dt = 0; dt < 10; dt++)
          accO[dt] = mfma16(aP, bV[dt], accO[dt]);
        __builtin_amdgcn_s_setprio(0);
      }
    }

    __builtin_amdgcn_s_barrier();
    if (more) {
#pragma unroll
      for (int i = 0; i < 5; i++) {
        int u = tid + 512 * i;
        if (u < 1280) { int row = u / 20, c = u % 20; *(uint4*)&Ks[row][c * 8] = rg[i]; }
        else { int v = u - 1280; int row = v >> 3, c = v & 7; *(uint4*)&Vs[row][c * 8] = rg[i]; }
      }
      asm volatile("s_waitcnt lgkmcnt(0)" ::: "memory");  // writes visible to other waves
    }
    __builtin_amdgcn_s_barrier();
  }

  float inv[4];
#pragma unroll
  for (int r = 0; r < 4; r++) inv[r] = 1.0f / lrun[r];
#pragma unroll
  for (int dt = 0; dt < 10; dt++)
#pragma unroll
    for (int r = 0; r < 4; r++) {
      int q = qb + l4 * 4 + r;
      ctx[(size_t)q * HID + h * HDIM + dt * 16 + l15] = f2bf(accO[dt][r] * inv[r]);
    }
}

// -----------------------------------------------------------------------------
extern "C" void kernel_launch(void* const* d_in, const int* in_sizes, int n_in,
                              void* d_out, int out_size, void* d_ws, size_t ws_size,
                              hipStream_t stream) {
  const float* hs    = (const float*)d_in[0];
  const float* resid = (const float*)d_in[1];
  // d_in[2] = attention_mask (causal triu) — implied by kernel, ignored
  const float* Wq  = (const float*)d_in[3];
  const float* Wkv = (const float*)d_in[4];
  const float* Wd  = (const float*)d_in[5];
  const float* bd  = (const float*)d_in[6];
  float* out = (float*)d_out;

  char* ws = (char*)d_ws;
  const size_t SH = (size_t)S_LEN * HID;          // 10,485,760
  u16* Xb     = (u16*)(ws);                        size_t off = SH * 2;
  u16* Wqkvb  = (u16*)(ws + off);                  off += (size_t)3 * HID * HID * 2; // [Wq rows | Wkv rows]
  u16* Wdb    = (u16*)(ws + off);                  off += (size_t)HID * HID * 2;
  u16* QKVraw = (u16*)(ws + off);                  off += (size_t)S_LEN * NQKV * 2;  // [2048][15360]
  u16* Qr     = (u16*)(ws + off);                  off += SH * 2;
  u16* Kr     = (u16*)(ws + off);                  off += SH * 2;
  u16* Vt     = (u16*)(ws + off);                  off += SH * 2;
  u16* ctx    = (u16*)(ws + off);                  off += SH * 2;
  float2* tab = (float2*)(ws + off);               off += (size_t)S_LEN * 80 * 8;

  // 1) one fused f32->bf16 pass: hs + Wq + Wkv + Wd
  cvt_all_kernel<<<2048, 256, 0, stream>>>(hs, Wq, Wkv, Wd, Xb, Wqkvb, Wdb);

  // 2) RoPE table
  rope_table_kernel<<<64, 256, 0, stream>>>(tab);

  // 3) fused QKV projection: [2048,15360] = Xb @ [Wq|Wkv]^T
  gemm256<0><<<dim3(NQKV / 256, S_LEN / 256), 512, 0, stream>>>(
      Xb, Wqkvb, QKVraw, S_LEN, NQKV, HID, nullptr, nullptr);

  // 4) RoPE Q+K in one launch; V transpose
  rope_apply2_kernel<<<2 * S_LEN * NHEAD * 80 / 256, 256, 0, stream>>>(QKVraw, tab, Qr, Kr);
  vtrans_kernel<<<dim3(S_LEN / 64, NHEAD), 256, 0, stream>>>(QKVraw + HID + HDIM, Vt, NQKV);

  // 5) attention (balanced pairing, raw barriers, 128 q-rows per block)
  attn_kernel<<<512, 512, 0, stream>>>(Qr, Kr, Vt, ctx);

  // 6) output projection + bias + residual (128² tile: 640 blocks fill the GPU)
  gemm_bt<1><<<dim3(HID / 128, S_LEN / 128), 256, 0, stream>>>(
      ctx, Wdb, out, S_LEN, HID, HID, bd, resid);
}

// Round 11
// 947.199 us; speedup vs baseline: 1.1191x; 1.0258x over previous
//
#include <hip/hip_runtime.h>
#include <cmath>

typedef unsigned short u16;
typedef unsigned int   u32;

using bf16x8 = __attribute__((ext_vector_type(8))) short;   // 8 bf16 in 4 VGPRs
using f32x4  = __attribute__((ext_vector_type(4))) float;

#define S_LEN 2048
#define NHEAD 32
#define HDIM  160
#define HID   5120   // NHEAD*HDIM
#define NQKV  15360  // HID + 2*HID

__device__ __forceinline__ f32x4 mfma16(bf16x8 a, bf16x8 b, f32x4 c) {
  return __builtin_amdgcn_mfma_f32_16x16x32_bf16(a, b, c, 0, 0, 0);
}

__device__ __forceinline__ u16 f2bf(float f) {          // RNE f32->bf16
  u32 u = __builtin_bit_cast(u32, f);
  u += 0x7FFFu + ((u >> 16) & 1u);
  return (u16)(u >> 16);
}
__device__ __forceinline__ float bf2f(u16 h) {
  u32 u = ((u32)h) << 16;
  return __builtin_bit_cast(float, u);
}

// async global->LDS, 16B per lane; LDS dest is wave-uniform base + lane*16
__device__ __forceinline__ void gload16(const void* g, void* l) {
  __builtin_amdgcn_global_load_lds((const __attribute__((address_space(1))) void*)g,
                                   (__attribute__((address_space(3))) void*)l, 16, 0, 0);
}

// ---------------- fused f32 -> bf16 convert for hs + Wq + Wkv + Wd ------------
__global__ void cvt_all_kernel(const float* __restrict__ hs, const float* __restrict__ Wq,
                               const float* __restrict__ Wkv, const float* __restrict__ Wd,
                               u16* __restrict__ Xb, u16* __restrict__ Wqkvb,
                               u16* __restrict__ Wdb) {
  const int n_hs = S_LEN * HID / 8;          // 1,310,720
  const int n_q  = HID * HID / 8;            // 3,276,800
  const int n_kv = 2 * HID * HID / 8;        // 6,553,600
  const int n_d  = HID * HID / 8;            // 3,276,800
  const int total = n_hs + n_q + n_kv + n_d; // 14,417,920
  for (int i = blockIdx.x * 256 + threadIdx.x; i < total; i += gridDim.x * 256) {
    const float* src; u16* dst; int j = i;
    if (j < n_hs)                { src = hs;  dst = Xb; }
    else if ((j -= n_hs) < n_q)  { src = Wq;  dst = Wqkvb; }
    else if ((j -= n_q) < n_kv)  { src = Wkv; dst = Wqkvb + (size_t)HID * HID; }
    else { j -= n_kv;              src = Wd;  dst = Wdb; }
    float4 a = ((const float4*)src)[(size_t)j * 2];
    float4 b = ((const float4*)src)[(size_t)j * 2 + 1];
    uint4 o;
    o.x = (u32)f2bf(a.x) | ((u32)f2bf(a.y) << 16);
    o.y = (u32)f2bf(a.z) | ((u32)f2bf(a.w) << 16);
    o.z = (u32)f2bf(b.x) | ((u32)f2bf(b.y) << 16);
    o.w = (u32)f2bf(b.z) | ((u32)f2bf(b.w) << 16);
    ((uint4*)dst)[j] = o;
  }
}

// ---------------- RoPE table: tab[s][j] = (cos, sin), j<80 -------------------
// eff=8192 -> mscale=1.0, ntk_alpha=3, base=10000*3^(160/158).
__global__ void rope_table_kernel(float2* __restrict__ tab) {
  __shared__ double invf_s[80];
  int tid = threadIdx.x;
  if (tid < 80) {
    double base = 10000.0 * pow(3.0, 160.0 / 158.0);
    invf_s[tid] = pow(base, -((double)(2 * tid)) / 160.0);
  }
  __syncthreads();
  for (int i = blockIdx.x * 256 + tid; i < S_LEN * 80; i += gridDim.x * 256) {
    int s = i / 80, j = i % 80;
    double ang = fmod((double)s * invf_s[j], 6.283185307179586476925287);
    float a = (float)ang;
    tab[i] = make_float2(cosf(a), sinf(a));
  }
}

// ---------------- RoPE apply (Q and K in one launch) + head-major relayout ----
__global__ void rope_apply2_kernel(const u16* __restrict__ qkv, const float2* __restrict__ tab,
                                   u16* __restrict__ Qr, u16* __restrict__ Kr) {
  const int n = S_LEN * NHEAD * 80;                 // per-slice dword-pairs
  int i = blockIdx.x * 256 + threadIdx.x;
  bool isK = i >= n;
  if (isK) i -= n;
  const u16* src = qkv + (isK ? HID : 0);
  int headStride = isK ? 2 * HDIM : HDIM;
  u16* dst = isK ? Kr : Qr;

  int dp = i % 80; int sh = i / 80; int h = sh % NHEAD; int s = sh / NHEAD;
  int d = 2 * dp;
  const u16* row = src + (size_t)s * NQKV + h * headStride;
  u32 q01 = *(const u32*)&row[d];
  u32 p01 = *(const u32*)&row[d < 80 ? d + 80 : d - 80];
  int j = (d < 80) ? d : d - 80;
  float2 cs0 = tab[s * 80 + j];
  float2 cs1 = tab[s * 80 + j + 1];
  float q0 = bf2f((u16)(q01 & 0xffff)), q1 = bf2f((u16)(q01 >> 16));
  float p0 = bf2f((u16)(p01 & 0xffff)), p1 = bf2f((u16)(p01 >> 16));
  float sgn = (d < 80) ? -1.f : 1.f;                // out = x*cos + rot_half(x)*sin
  float o0 = q0 * cs0.x + sgn * p0 * cs0.y;
  float o1 = q1 * cs1.x + sgn * p1 * cs1.y;
  u32 o = (u32)f2bf(o0) | ((u32)f2bf(o1) << 16);
  *(u32*)&dst[((size_t)h * S_LEN + s) * HDIM + d] = o;
}

// ---------------- V transpose: v-slice of fused QKV -> Vt[h][d][s] -----------
__global__ void vtrans_kernel(const u16* __restrict__ src, u16* __restrict__ Vt, int rowStride) {
  __shared__ u16 T[HDIM][72];                       // pad 64->72 (2-way max on reads)
  int h = blockIdx.y; int s0 = blockIdx.x * 64; int tid = threadIdx.x;
  for (int i = tid; i < 64 * 80; i += 256) {
    int s = i / 80, dp = i % 80;
    u32 v = *(const u32*)&src[(size_t)(s0 + s) * rowStride + h * 320 + 2 * dp];
    T[2 * dp][s]     = (u16)(v & 0xffff);
    T[2 * dp + 1][s] = (u16)(v >> 16);
  }
  __syncthreads();
  for (int i = tid; i < HDIM * 32; i += 256) {
    int d = i / 32, sp = i % 32;
    u32 v = (u32)T[d][2 * sp] | ((u32)T[d][2 * sp + 1] << 16);
    *(u32*)&Vt[((size_t)h * HDIM + d) * S_LEN + s0 + 2 * sp] = v;
  }
}

// ---------------- GEMM 256(M)x128(N), BK=32, 2 blocks/CU (TLP overlap) --------
// C[M,N] = A[M,K] @ B[N,K]^T, bf16 in, f32 acc. 512 thr = 8 waves (4M x 2N) of
// 64x64 each: acc = 64 AGPR -> total regs ~115 < 128 -> 4 waves/SIMD; LDS 48 KB
// (dbuf: A 16K + B 8K) -> 2 blocks/CU. R10's 1-block/CU 8-phase alternated
// LDS-read and MFMA windows under lockstep barriers (2300+2480 cyc/iter
// serialized = measured 36% MfmaUtil); a second resident block fills each
// window (m114 co-schedule; m97's multi-block recipe). Counted vmcnt(3) + raw
// barriers; st_16x32 swizzle both sides (R5-verified 0 conflicts).
template<int EPI>
__global__ __launch_bounds__(512, 4) void gemm256(
    const u16* __restrict__ A, const u16* __restrict__ Bm, void* __restrict__ Cout,
    int M, int N, int K, const float* __restrict__ bias, const float* __restrict__ resid)
{
  __shared__ u16 As[2][8192];    // [dbuf][256 rows x 32 cols]  16 KB/buf
  __shared__ u16 Bs[2][4096];    // [dbuf][128 rows x 32 cols]   8 KB/buf
  int tid = threadIdx.x;
  int w = tid >> 6, l = tid & 63, l15 = l & 15, l4 = l >> 4;
  int wr = w >> 1, wc = w & 1;   // 4 x 2 wave grid of 64x64 tiles

  // XCD chunked swizzle (nwg % 8 == 0; 120-block chunk = one A row-panel/XCD)
  int nbx = gridDim.x;
  int nwg = nbx * gridDim.y;
  int lin = blockIdx.y * nbx + blockIdx.x;
  int cpx = nwg >> 3;
  int swz = (lin & 7) * cpx + (lin >> 3);
  int bm = (swz / nbx) * 256, bn = (swz % nbx) * 128;

  int srow = tid >> 2;                                  // 0..127
  int scol = ((tid & 3) * 8) ^ ((srow & 8) ? 16 : 0);   // pre-swizzled source col
  const u16* gA0 = A + (size_t)(bm + srow) * K + scol;  // A rows 0..127
  const u16* gA1 = gA0 + (size_t)128 * K;               // A rows 128..255
  const u16* gB  = Bm + (size_t)(bn + srow) * K + scol; // B rows 0..127
  int w512 = w * 512;                                   // wave-uniform dest (elems)

  f32x4 acc[4][4];
#pragma unroll
  for (int i = 0; i < 4; i++)
#pragma unroll
    for (int j = 0; j < 4; j++) acc[i][j] = f32x4{0.f, 0.f, 0.f, 0.f};

  int cA = (l4 * 8) ^ ((l15 & 8) ? 16 : 0);             // read-side swizzle (const)
  const int NT = K >> 5;                                // 160 for K=5120
  int arow = wr * 64;                                   // wave A row base
  int brow = wc * 64;                                   // wave B row base

  auto STAGE = [&](int kt) { int p = kt & 1, ko = kt << 5;
    gload16(gA0 + ko, &As[p][w512]);
    gload16(gA1 + ko, &As[p][4096 + w512]);
    gload16(gB  + ko, &Bs[p][w512]);
  };

  STAGE(0);
  for (int kt = 0; kt < NT; ++kt) {
    int p = kt & 1;
    if (kt + 1 < NT) {
      STAGE(kt + 1);                       // writes buf p^1 (reads done iter kt-1)
      asm volatile("s_waitcnt vmcnt(3)" ::: "memory");   // tile kt landed (this wave)
    } else {
      asm volatile("s_waitcnt vmcnt(0)" ::: "memory");
    }
    __builtin_amdgcn_s_barrier();          // all waves' tile-kt loads visible

    bf16x8 aF[4], bF[4];
#pragma unroll
    for (int mi = 0; mi < 4; ++mi)
      aF[mi] = *(const bf16x8*)&As[p][(arow + mi * 16 + l15) * 32 + cA];
#pragma unroll
    for (int ni = 0; ni < 4; ++ni)
      bF[ni] = *(const bf16x8*)&Bs[p][(brow + ni * 16 + l15) * 32 + cA];
    __builtin_amdgcn_s_setprio(1);
#pragma unroll
    for (int mi = 0; mi < 4; ++mi)
#pragma unroll
      for (int ni = 0; ni < 4; ++ni)
        acc[mi][ni] = mfma16(aF[mi], bF[ni], acc[mi][ni]);
    __builtin_amdgcn_s_setprio(0);
    __builtin_amdgcn_s_barrier();          // tile-kt reads complete block-wide
  }

#pragma unroll
  for (int mi = 0; mi < 4; ++mi)
#pragma unroll
    for (int ni = 0; ni < 4; ++ni) {
      int row0 = bm + wr * 64 + mi * 16 + l4 * 4;
      int col  = bn + wc * 64 + ni * 16 + l15;
      if (EPI == 0) {
        u16* C = (u16*)Cout;
#pragma unroll
        for (int r = 0; r < 4; r++) C[(size_t)(row0 + r) * N + col] = f2bf(acc[mi][ni][r]);
      } else {
        float* C = (float*)Cout;
        float b = bias[col];
#pragma unroll
        for (int r = 0; r < 4; r++) {
          size_t idx = (size_t)(row0 + r) * N + col;
          C[idx] = acc[mi][ni][r] + b + resid[idx];
        }
      }
    }
}

// ---------------- GEMM 128x128 (m97 structure; proj only — 640 blocks fill GPU)
template<int EPI>
__global__ __launch_bounds__(256, 2) void gemm_bt(
    const u16* __restrict__ A, const u16* __restrict__ Bm, void* __restrict__ Cout,
    int M, int N, int K, const float* __restrict__ bias, const float* __restrict__ resid)
{
  int tid = threadIdx.x;
  int wv = tid >> 6, l = tid & 63, l15 = l & 15, l4 = l >> 4;
  int nbx = gridDim.x;
  int nwg = nbx * gridDim.y;
  int lin = blockIdx.y * nbx + blockIdx.x;
  int cpx = nwg >> 3;
  int swz = (lin & 7) * cpx + (lin >> 3);
  int bm = (swz / nbx) * 128, bn = (swz % nbx) * 128;

  __shared__ u16 As[128 * 32], Bs[128 * 32];
  f32x4 acc[4][4];
#pragma unroll
  for (int i = 0; i < 4; i++)
#pragma unroll
    for (int j = 0; j < 4; j++) acc[i][j] = f32x4{0.f, 0.f, 0.f, 0.f};

  int wm = (wv >> 1) * 64, wn = (wv & 1) * 64;
  const u16* gA = A + (size_t)(bm + (tid >> 2)) * K + (tid & 3) * 8;
  const u16* gB = Bm + (size_t)(bn + (tid >> 2)) * K + (tid & 3) * 8;
  u16* ldsA = As + wv * 16 * 32;
  u16* ldsB = Bs + wv * 16 * 32;

  for (int k0 = 0; k0 < K; k0 += 32) {
    __syncthreads();
    gload16(gA + k0, ldsA);
    gload16(gA + (size_t)64 * K + k0, ldsA + 64 * 32);
    gload16(gB + k0, ldsB);
    gload16(gB + (size_t)64 * K + k0, ldsB + 64 * 32);
    __syncthreads();
    bf16x8 af[4], bfr[4];
#pragma unroll
    for (int i = 0; i < 4; i++) af[i] = *(const bf16x8*)&As[(wm + i * 16 + l15) * 32 + l4 * 8];
#pragma unroll
    for (int i = 0; i < 4; i++) bfr[i] = *(const bf16x8*)&Bs[(wn + i * 16 + l15) * 32 + l4 * 8];
#pragma unroll
    for (int mi = 0; mi < 4; mi++)
#pragma unroll
      for (int ni = 0; ni < 4; ni++) acc[mi][ni] = mfma16(af[mi], bfr[ni], acc[mi][ni]);
  }

#pragma unroll
  for (int mi = 0; mi < 4; mi++)
#pragma unroll
    for (int ni = 0; ni < 4; ni++) {
      int row0 = bm + wm + mi * 16 + l4 * 4;
      int col  = bn + wn + ni * 16 + l15;
      if (EPI == 0) {
        u16* C = (u16*)Cout;
#pragma unroll
        for (int r = 0; r < 4; r++) C[(size_t)(row0 + r) * N + col] = f2bf(acc[mi][ni][r]);
      } else {
        float* C = (float*)Cout;
        float b = bias[col];
#pragma unroll
        for (int r = 0; r < 4; r++) {
          size_t idx = (size_t)(row0 + r) * N + col;
          C[idx] = acc[mi][ni][r] + b + resid[idx];
        }
      }
    }
}

// ---------------- Flash attention v4 (causal, LDS-staged K/V) -----------------
__global__ __launch_bounds__(512, 4) void attn_kernel(
    const u16* __restrict__ Qr, const u16* __restrict__ Kr,
    const u16* __restrict__ Vt, u16* __restrict__ ctx)
{
  int lin = blockIdx.x;
  int h  = lin & 31;               // same head -> same XCD (lin%8 == h%8 both halves)
  int qx = (lin < 256) ? (15 - (lin >> 5)) : ((lin - 256) >> 5);
  int q0 = qx * 128;
  int tid = threadIdx.x;
  int w = tid >> 6, l = tid & 63, l15 = l & 15, l4 = l >> 4;
  int qb = q0 + w * 16;

  __shared__ u16 Ks[64][164];      // 328B row stride: <=2-way on frag reads
  __shared__ u16 Vs[160][68];      // 136B row stride: conflict-free reads
  __shared__ u16 Plds[8][16][68];  // per-wave P tile

  const u16* Qh = Qr + (size_t)h * S_LEN * HDIM;
  const u16* Kh = Kr + (size_t)h * S_LEN * HDIM;
  const u16* Vh = Vt + (size_t)h * HDIM * S_LEN;

  bf16x8 aQ[5];
#pragma unroll
  for (int kc = 0; kc < 5; kc++)
    aQ[kc] = *(const bf16x8*)&Qh[(size_t)(qb + l15) * HDIM + kc * 32 + l4 * 8];

  f32x4 accO[10];
#pragma unroll
  for (int dt = 0; dt < 10; dt++) accO[dt] = f32x4{0.f, 0.f, 0.f, 0.f};
  float mrun[4], lrun[4];
#pragma unroll
  for (int r = 0; r < 4; r++) { mrun[r] = -1e30f; lrun[r] = 0.f; }

  const float c2 = 0.07905694150420949f * 1.44269504088896f;  // 1/sqrt(160)*log2(e)
  int Tend = 2 * qx + 2;           // k tiles cover k <= q0+127

  {
    uint4 rg[5];
#pragma unroll
    for (int i = 0; i < 5; i++) {
      int u = tid + 512 * i;
      if (u < 1280) { int row = u / 20, c = u % 20;
        rg[i] = *(const uint4*)&Kh[(size_t)row * HDIM + c * 8]; }
      else { int v = u - 1280; int row = v >> 3, c = v & 7;
        rg[i] = *(const uint4*)&Vh[(size_t)row * S_LEN + c * 8]; }
    }
#pragma unroll
    for (int i = 0; i < 5; i++) {
      int u = tid + 512 * i;
      if (u < 1280) { int row = u / 20, c = u % 20; *(uint4*)&Ks[row][c * 8] = rg[i]; }
      else { int v = u - 1280; int row = v >> 3, c = v & 7; *(uint4*)&Vs[row][c * 8] = rg[i]; }
    }
  }
  __syncthreads();

  for (int t = 0; t < Tend; ++t) {
    int k0 = t * 64;
    bool more = (t + 1 < Tend);
    uint4 rg[5];
    if (more) {                     // issue next-tile loads early (T14)
      int k1 = k0 + 64;
#pragma unroll
      for (int i = 0; i < 5; i++) {
        int u = tid + 512 * i;
        if (u < 1280) { int row = u / 20, c = u % 20;
          rg[i] = *(const uint4*)&Kh[(size_t)(k1 + row) * HDIM + c * 8]; }
        else { int v = u - 1280; int row = v >> 3, c = v & 7;
          rg[i] = *(const uint4*)&Vh[(size_t)row * S_LEN + k1 + c * 8]; }
      }
    }

    if (k0 <= qb + 15) {            // wave-active (causal tile skip)
      f32x4 s_[4];
#pragma unroll
      for (int nt = 0; nt < 4; nt++) s_[nt] = f32x4{0.f, 0.f, 0.f, 0.f};

#pragma unroll
      for (int kc = 0; kc < 5; kc++) {
        bf16x8 bK[4];
#pragma unroll
        for (int nt = 0; nt < 4; nt++)
          bK[nt] = *(const bf16x8*)&Ks[nt * 16 + l15][kc * 32 + l4 * 8];
        __builtin_amdgcn_s_setprio(1);
#pragma unroll
        for (int nt = 0; nt < 4; nt++) s_[nt] = mfma16(aQ[kc], bK[nt], s_[nt]);
        __builtin_amdgcn_s_setprio(0);
      }

      if (k0 + 63 > qb) {           // diagonal-region mask
#pragma unroll
        for (int nt = 0; nt < 4; nt++)
#pragma unroll
          for (int r = 0; r < 4; r++) {
            int kk = k0 + nt * 16 + l15;
            int qq = qb + l4 * 4 + r;
            if (kk > qq) s_[nt][r] = -1e30f;
          }
      }

      float sf[4];
#pragma unroll
      for (int r = 0; r < 4; r++) {
        float v = fmaxf(fmaxf(s_[0][r], s_[1][r]), fmaxf(s_[2][r], s_[3][r]));
#pragma unroll
        for (int m = 1; m <= 8; m <<= 1) v = fmaxf(v, __shfl_xor(v, m));
        float mnew = fmaxf(mrun[r], v);
        sf[r] = exp2f((mrun[r] - mnew) * c2);
        mrun[r] = mnew;
      }
      float rsum[4] = {0.f, 0.f, 0.f, 0.f};
#pragma unroll
      for (int nt = 0; nt < 4; nt++)
#pragma unroll
        for (int r = 0; r < 4; r++) {
          float p = exp2f((s_[nt][r] - mrun[r]) * c2);
          s_[nt][r] = p;
          rsum[r] += p;
        }
#pragma unroll
      for (int r = 0; r < 4; r++) {
        float v = rsum[r];
#pragma unroll
        for (int m = 1; m <= 8; m <<= 1) v += __shfl_xor(v, m);
        lrun[r] = lrun[r] * sf[r] + v;
      }
#pragma unroll
      for (int dt = 0; dt < 10; dt++)
#pragma unroll
        for (int r = 0; r < 4; r++) accO[dt][r] *= sf[r];
#pragma unroll
      for (int nt = 0; nt < 4; nt++)
#pragma unroll
        for (int r = 0; r < 4; r++)
          Plds[w][l4 * 4 + r][nt * 16 + l15] = f2bf(s_[nt][r]);

      // PV: A = P (wave-local LDS), B = V rows (block LDS)
#pragma unroll
      for (int kc = 0; kc < 2; kc++) {
        bf16x8 aP = *(const bf16x8*)&Plds[w][l15][kc * 32 + l4 * 8];
        bf16x8 bV[10];
#pragma unroll
        for (int dt = 0; dt < 10; dt++)
          bV[dt] = *(const bf16x8*)&Vs[dt * 16 + l15][kc * 32 + l4 * 8];
        __builtin_amdgcn_s_setprio(1);
#pragma unroll
        for (int dt = 0; dt < 10; dt++)
          accO[dt] = mfma16(aP, bV[dt], accO[dt]);
        __builtin_amdgcn_s_setprio(0);
      }
    }

    __builtin_amdgcn_s_barrier();
    if (more) {
#pragma unroll
      for (int i = 0; i < 5; i++) {
        int u = tid + 512 * i;
        if (u < 1280) { int row = u / 20, c = u % 20; *(uint4*)&Ks[row][c * 8] = rg[i]; }
        else { int v = u - 1280; int row = v >> 3, c = v & 7; *(uint4*)&Vs[row][c * 8] = rg[i]; }
      }
      asm volatile("s_waitcnt lgkmcnt(0)" ::: "memory");  // writes visible to other waves
    }
    __builtin_amdgcn_s_barrier();
  }

  float inv[4];
#pragma unroll
  for (int r = 0; r < 4; r++) inv[r] = 1.0f / lrun[r];
#pragma unroll
  for (int dt = 0; dt < 10; dt++)
#pragma unroll
    for (int r = 0; r < 4; r++) {
      int q = qb + l4 * 4 + r;
      ctx[(size_t)q * HID + h * HDIM + dt * 16 + l15] = f2bf(accO[dt][r] * inv[r]);
    }
}

// -----------------------------------------------------------------------------
extern "C" void kernel_launch(void* const* d_in, const int* in_sizes, int n_in,
                              void* d_out, int out_size, void* d_ws, size_t ws_size,
                              hipStream_t stream) {
  const float* hs    = (const float*)d_in[0];
  const float* resid = (const float*)d_in[1];
  // d_in[2] = attention_mask (causal triu) — implied by kernel, ignored
  const float* Wq  = (const float*)d_in[3];
  const float* Wkv = (const float*)d_in[4];
  const float* Wd  = (const float*)d_in[5];
  const float* bd  = (const float*)d_in[6];
  float* out = (float*)d_out;

  char* ws = (char*)d_ws;
  const size_t SH = (size_t)S_LEN * HID;          // 10,485,760
  u16* Xb     = (u16*)(ws);                        size_t off = SH * 2;
  u16* Wqkvb  = (u16*)(ws + off);                  off += (size_t)3 * HID * HID * 2; // [Wq rows | Wkv rows]
  u16* Wdb    = (u16*)(ws + off);                  off += (size_t)HID * HID * 2;
  u16* QKVraw = (u16*)(ws + off);                  off += (size_t)S_LEN * NQKV * 2;  // [2048][15360]
  u16* Qr     = (u16*)(ws + off);                  off += SH * 2;
  u16* Kr     = (u16*)(ws + off);                  off += SH * 2;
  u16* Vt     = (u16*)(ws + off);                  off += SH * 2;
  u16* ctx    = (u16*)(ws + off);                  off += SH * 2;
  float2* tab = (float2*)(ws + off);               off += (size_t)S_LEN * 80 * 8;

  // 1) one fused f32->bf16 pass: hs + Wq + Wkv + Wd
  cvt_all_kernel<<<2048, 256, 0, stream>>>(hs, Wq, Wkv, Wd, Xb, Wqkvb, Wdb);

  // 2) RoPE table
  rope_table_kernel<<<64, 256, 0, stream>>>(tab);

  // 3) fused QKV projection: [2048,15360] = Xb @ [Wq|Wkv]^T  (256x128 tiles)
  gemm256<0><<<dim3(NQKV / 128, S_LEN / 256), 512, 0, stream>>>(
      Xb, Wqkvb, QKVraw, S_LEN, NQKV, HID, nullptr, nullptr);

  // 4) RoPE Q+K in one launch; V transpose
  rope_apply2_kernel<<<2 * S_LEN * NHEAD * 80 / 256, 256, 0, stream>>>(QKVraw, tab, Qr, Kr);
  vtrans_kernel<<<dim3(S_LEN / 64, NHEAD), 256, 0, stream>>>(QKVraw + HID + HDIM, Vt, NQKV);

  // 5) attention (balanced pairing, raw barriers, 128 q-rows per block)
  attn_kernel<<<512, 512, 0, stream>>>(Qr, Kr, Vt, ctx);

  // 6) output projection + bias + residual (128² tile: 640 blocks fill the GPU)
  gemm_bt<1><<<dim3(HID / 128, S_LEN / 128), 256, 0, stream>>>(
      ctx, Wdb, out, S_LEN, HID, HID, bd, resid);
}

// Round 12
// 944.771 us; speedup vs baseline: 1.1220x; 1.0026x over previous
//
#include <hip/hip_runtime.h>
#include <cmath>

typedef unsigned short u16;
typedef unsigned int   u32;

using bf16x8 = __attribute__((ext_vector_type(8))) short;   // 8 bf16 in 4 VGPRs
using f32x4  = __attribute__((ext_vector_type(4))) float;

#define S_LEN 2048
#define NHEAD 32
#define HDIM  160
#define HID   5120   // NHEAD*HDIM
#define NQKV  15360  // HID + 2*HID

__device__ __forceinline__ f32x4 mfma16(bf16x8 a, bf16x8 b, f32x4 c) {
  return __builtin_amdgcn_mfma_f32_16x16x32_bf16(a, b, c, 0, 0, 0);
}

__device__ __forceinline__ u16 f2bf(float f) {          // RNE f32->bf16
  u32 u = __builtin_bit_cast(u32, f);
  u += 0x7FFFu + ((u >> 16) & 1u);
  return (u16)(u >> 16);
}
__device__ __forceinline__ float bf2f(u16 h) {
  u32 u = ((u32)h) << 16;
  return __builtin_bit_cast(float, u);
}

// async global->LDS, 16B per lane; LDS dest is wave-uniform base + lane*16
__device__ __forceinline__ void gload16(const void* g, void* l) {
  __builtin_amdgcn_global_load_lds((const __attribute__((address_space(1))) void*)g,
                                   (__attribute__((address_space(3))) void*)l, 16, 0, 0);
}

// ---------------- fused f32 -> bf16 convert for hs + Wq + Wkv + Wd ------------
__global__ void cvt_all_kernel(const float* __restrict__ hs, const float* __restrict__ Wq,
                               const float* __restrict__ Wkv, const float* __restrict__ Wd,
                               u16* __restrict__ Xb, u16* __restrict__ Wqkvb,
                               u16* __restrict__ Wdb) {
  const int n_hs = S_LEN * HID / 8;          // 1,310,720
  const int n_q  = HID * HID / 8;            // 3,276,800
  const int n_kv = 2 * HID * HID / 8;        // 6,553,600
  const int n_d  = HID * HID / 8;            // 3,276,800
  const int total = n_hs + n_q + n_kv + n_d; // 14,417,920
  for (int i = blockIdx.x * 256 + threadIdx.x; i < total; i += gridDim.x * 256) {
    const float* src; u16* dst; int j = i;
    if (j < n_hs)                { src = hs;  dst = Xb; }
    else if ((j -= n_hs) < n_q)  { src = Wq;  dst = Wqkvb; }
    else if ((j -= n_q) < n_kv)  { src = Wkv; dst = Wqkvb + (size_t)HID * HID; }
    else { j -= n_kv;              src = Wd;  dst = Wdb; }
    float4 a = ((const float4*)src)[(size_t)j * 2];
    float4 b = ((const float4*)src)[(size_t)j * 2 + 1];
    uint4 o;
    o.x = (u32)f2bf(a.x) | ((u32)f2bf(a.y) << 16);
    o.y = (u32)f2bf(a.z) | ((u32)f2bf(a.w) << 16);
    o.z = (u32)f2bf(b.x) | ((u32)f2bf(b.y) << 16);
    o.w = (u32)f2bf(b.z) | ((u32)f2bf(b.w) << 16);
    ((uint4*)dst)[j] = o;
  }
}

// ---------------- RoPE table: tab[s][j] = (cos, sin), j<80 -------------------
// eff=8192 -> mscale=1.0, ntk_alpha=3, base=10000*3^(160/158).
__global__ void rope_table_kernel(float2* __restrict__ tab) {
  __shared__ double invf_s[80];
  int tid = threadIdx.x;
  if (tid < 80) {
    double base = 10000.0 * pow(3.0, 160.0 / 158.0);
    invf_s[tid] = pow(base, -((double)(2 * tid)) / 160.0);
  }
  __syncthreads();
  for (int i = blockIdx.x * 256 + tid; i < S_LEN * 80; i += gridDim.x * 256) {
    int s = i / 80, j = i % 80;
    double ang = fmod((double)s * invf_s[j], 6.283185307179586476925287);
    float a = (float)ang;
    tab[i] = make_float2(cosf(a), sinf(a));
  }
}

// ---------------- RoPE apply (Q and K in one launch) + head-major relayout ----
__global__ void rope_apply2_kernel(const u16* __restrict__ qkv, const float2* __restrict__ tab,
                                   u16* __restrict__ Qr, u16* __restrict__ Kr) {
  const int n = S_LEN * NHEAD * 80;                 // per-slice dword-pairs
  int i = blockIdx.x * 256 + threadIdx.x;
  bool isK = i >= n;
  if (isK) i -= n;
  const u16* src = qkv + (isK ? HID : 0);
  int headStride = isK ? 2 * HDIM : HDIM;
  u16* dst = isK ? Kr : Qr;

  int dp = i % 80; int sh = i / 80; int h = sh % NHEAD; int s = sh / NHEAD;
  int d = 2 * dp;
  const u16* row = src + (size_t)s * NQKV + h * headStride;
  u32 q01 = *(const u32*)&row[d];
  u32 p01 = *(const u32*)&row[d < 80 ? d + 80 : d - 80];
  int j = (d < 80) ? d : d - 80;
  float2 cs0 = tab[s * 80 + j];
  float2 cs1 = tab[s * 80 + j + 1];
  float q0 = bf2f((u16)(q01 & 0xffff)), q1 = bf2f((u16)(q01 >> 16));
  float p0 = bf2f((u16)(p01 & 0xffff)), p1 = bf2f((u16)(p01 >> 16));
  float sgn = (d < 80) ? -1.f : 1.f;                // out = x*cos + rot_half(x)*sin
  float o0 = q0 * cs0.x + sgn * p0 * cs0.y;
  float o1 = q1 * cs1.x + sgn * p1 * cs1.y;
  u32 o = (u32)f2bf(o0) | ((u32)f2bf(o1) << 16);
  *(u32*)&dst[((size_t)h * S_LEN + s) * HDIM + d] = o;
}

// ---------------- V transpose: v-slice of fused QKV -> Vt[h][d][s] -----------
__global__ void vtrans_kernel(const u16* __restrict__ src, u16* __restrict__ Vt, int rowStride) {
  __shared__ u16 T[HDIM][72];                       // pad 64->72 (2-way max on reads)
  int h = blockIdx.y; int s0 = blockIdx.x * 64; int tid = threadIdx.x;
  for (int i = tid; i < 64 * 80; i += 256) {
    int s = i / 80, dp = i % 80;
    u32 v = *(const u32*)&src[(size_t)(s0 + s) * rowStride + h * 320 + 2 * dp];
    T[2 * dp][s]     = (u16)(v & 0xffff);
    T[2 * dp + 1][s] = (u16)(v >> 16);
  }
  __syncthreads();
  for (int i = tid; i < HDIM * 32; i += 256) {
    int d = i / 32, sp = i % 32;
    u32 v = (u32)T[d][2 * sp] | ((u32)T[d][2 * sp + 1] << 16);
    *(u32*)&Vt[((size_t)h * HDIM + d) * S_LEN + s0 + 2 * sp] = v;
  }
}

// ---------------- GEMM 256(M)x128(N), BK=32, 2 blocks/CU (TLP overlap) --------
// R11-measured: 845 TF, MfmaUtil 38.5, Occupancy 42%, 0 bank conflicts. FROZEN.
template<int EPI>
__global__ __launch_bounds__(512, 4) void gemm256(
    const u16* __restrict__ A, const u16* __restrict__ Bm, void* __restrict__ Cout,
    int M, int N, int K, const float* __restrict__ bias, const float* __restrict__ resid)
{
  __shared__ u16 As[2][8192];    // [dbuf][256 rows x 32 cols]  16 KB/buf
  __shared__ u16 Bs[2][4096];    // [dbuf][128 rows x 32 cols]   8 KB/buf
  int tid = threadIdx.x;
  int w = tid >> 6, l = tid & 63, l15 = l & 15, l4 = l >> 4;
  int wr = w >> 1, wc = w & 1;   // 4 x 2 wave grid of 64x64 tiles

  int nbx = gridDim.x;
  int nwg = nbx * gridDim.y;
  int lin = blockIdx.y * nbx + blockIdx.x;
  int cpx = nwg >> 3;
  int swz = (lin & 7) * cpx + (lin >> 3);
  int bm = (swz / nbx) * 256, bn = (swz % nbx) * 128;

  int srow = tid >> 2;                                  // 0..127
  int scol = ((tid & 3) * 8) ^ ((srow & 8) ? 16 : 0);   // pre-swizzled source col
  const u16* gA0 = A + (size_t)(bm + srow) * K + scol;  // A rows 0..127
  const u16* gA1 = gA0 + (size_t)128 * K;               // A rows 128..255
  const u16* gB  = Bm + (size_t)(bn + srow) * K + scol; // B rows 0..127
  int w512 = w * 512;                                   // wave-uniform dest (elems)

  f32x4 acc[4][4];
#pragma unroll
  for (int i = 0; i < 4; i++)
#pragma unroll
    for (int j = 0; j < 4; j++) acc[i][j] = f32x4{0.f, 0.f, 0.f, 0.f};

  int cA = (l4 * 8) ^ ((l15 & 8) ? 16 : 0);             // read-side swizzle (const)
  const int NT = K >> 5;                                // 160 for K=5120
  int arow = wr * 64;
  int brow = wc * 64;

  auto STAGE = [&](int kt) { int p = kt & 1, ko = kt << 5;
    gload16(gA0 + ko, &As[p][w512]);
    gload16(gA1 + ko, &As[p][4096 + w512]);
    gload16(gB  + ko, &Bs[p][w512]);
  };

  STAGE(0);
  for (int kt = 0; kt < NT; ++kt) {
    int p = kt & 1;
    if (kt + 1 < NT) {
      STAGE(kt + 1);                       // writes buf p^1 (reads done iter kt-1)
      asm volatile("s_waitcnt vmcnt(3)" ::: "memory");   // tile kt landed (this wave)
    } else {
      asm volatile("s_waitcnt vmcnt(0)" ::: "memory");
    }
    __builtin_amdgcn_s_barrier();          // all waves' tile-kt loads visible

    bf16x8 aF[4], bF[4];
#pragma unroll
    for (int mi = 0; mi < 4; ++mi)
      aF[mi] = *(const bf16x8*)&As[p][(arow + mi * 16 + l15) * 32 + cA];
#pragma unroll
    for (int ni = 0; ni < 4; ++ni)
      bF[ni] = *(const bf16x8*)&Bs[p][(brow + ni * 16 + l15) * 32 + cA];
    __builtin_amdgcn_s_setprio(1);
#pragma unroll
    for (int mi = 0; mi < 4; ++mi)
#pragma unroll
      for (int ni = 0; ni < 4; ++ni)
        acc[mi][ni] = mfma16(aF[mi], bF[ni], acc[mi][ni]);
    __builtin_amdgcn_s_setprio(0);
    __builtin_amdgcn_s_barrier();          // tile-kt reads complete block-wide
  }

#pragma unroll
  for (int mi = 0; mi < 4; ++mi)
#pragma unroll
    for (int ni = 0; ni < 4; ++ni) {
      int row0 = bm + wr * 64 + mi * 16 + l4 * 4;
      int col  = bn + wc * 64 + ni * 16 + l15;
      if (EPI == 0) {
        u16* C = (u16*)Cout;
#pragma unroll
        for (int r = 0; r < 4; r++) C[(size_t)(row0 + r) * N + col] = f2bf(acc[mi][ni][r]);
      } else {
        float* C = (float*)Cout;
        float b = bias[col];
#pragma unroll
        for (int r = 0; r < 4; r++) {
          size_t idx = (size_t)(row0 + r) * N + col;
          C[idx] = acc[mi][ni][r] + b + resid[idx];
        }
      }
    }
}

// ---------------- GEMM 128x128 (m97 structure; proj only — 640 blocks fill GPU)
template<int EPI>
__global__ __launch_bounds__(256, 2) void gemm_bt(
    const u16* __restrict__ A, const u16* __restrict__ Bm, void* __restrict__ Cout,
    int M, int N, int K, const float* __restrict__ bias, const float* __restrict__ resid)
{
  int tid = threadIdx.x;
  int wv = tid >> 6, l = tid & 63, l15 = l & 15, l4 = l >> 4;
  int nbx = gridDim.x;
  int nwg = nbx * gridDim.y;
  int lin = blockIdx.y * nbx + blockIdx.x;
  int cpx = nwg >> 3;
  int swz = (lin & 7) * cpx + (lin >> 3);
  int bm = (swz / nbx) * 128, bn = (swz % nbx) * 128;

  __shared__ u16 As[128 * 32], Bs[128 * 32];
  f32x4 acc[4][4];
#pragma unroll
  for (int i = 0; i < 4; i++)
#pragma unroll
    for (int j = 0; j < 4; j++) acc[i][j] = f32x4{0.f, 0.f, 0.f, 0.f};

  int wm = (wv >> 1) * 64, wn = (wv & 1) * 64;
  const u16* gA = A + (size_t)(bm + (tid >> 2)) * K + (tid & 3) * 8;
  const u16* gB = Bm + (size_t)(bn + (tid >> 2)) * K + (tid & 3) * 8;
  u16* ldsA = As + wv * 16 * 32;
  u16* ldsB = Bs + wv * 16 * 32;

  for (int k0 = 0; k0 < K; k0 += 32) {
    __syncthreads();
    gload16(gA + k0, ldsA);
    gload16(gA + (size_t)64 * K + k0, ldsA + 64 * 32);
    gload16(gB + k0, ldsB);
    gload16(gB + (size_t)64 * K + k0, ldsB + 64 * 32);
    __syncthreads();
    bf16x8 af[4], bfr[4];
#pragma unroll
    for (int i = 0; i < 4; i++) af[i] = *(const bf16x8*)&As[(wm + i * 16 + l15) * 32 + l4 * 8];
#pragma unroll
    for (int i = 0; i < 4; i++) bfr[i] = *(const bf16x8*)&Bs[(wn + i * 16 + l15) * 32 + l4 * 8];
#pragma unroll
    for (int mi = 0; mi < 4; mi++)
#pragma unroll
      for (int ni = 0; ni < 4; ni++) acc[mi][ni] = mfma16(af[mi], bfr[ni], acc[mi][ni]);
  }

#pragma unroll
  for (int mi = 0; mi < 4; mi++)
#pragma unroll
    for (int ni = 0; ni < 4; ni++) {
      int row0 = bm + wm + mi * 16 + l4 * 4;
      int col  = bn + wn + ni * 16 + l15;
      if (EPI == 0) {
        u16* C = (u16*)Cout;
#pragma unroll
        for (int r = 0; r < 4; r++) C[(size_t)(row0 + r) * N + col] = f2bf(acc[mi][ni][r]);
      } else {
        float* C = (float*)Cout;
        float b = bias[col];
#pragma unroll
        for (int r = 0; r < 4; r++) {
          size_t idx = (size_t)(row0 + r) * N + col;
          C[idx] = acc[mi][ni][r] + b + resid[idx];
        }
      }
    }
}

// ---------------- Flash attention v5: 4 waves x 32 q-rows ---------------------
// Same 512 blocks / 128 q-rows / KVBLK=64 / heavy+light CU pairing (34 tiles/CU)
// as v4, but 4 waves of 32 rows instead of 8 of 16: per-wave K/V LDS reads are
// unchanged while wave count halves -> block LDS traffic per tile-step drops
// ~40% (bK/bV multiplicity), softmax shuffle duplication halves, MFMA/wave
// doubles (40 QK + 40 PV). VGPR ~212 -> 2 waves/SIMD; LDS 60 KB -> 2 blocks/CU.
__global__ __launch_bounds__(256, 2) void attn_kernel(
    const u16* __restrict__ Qr, const u16* __restrict__ Kr,
    const u16* __restrict__ Vt, u16* __restrict__ ctx)
{
  int lin = blockIdx.x;
  int h  = lin & 31;               // same head -> same XCD (lin%8 == h%8 both halves)
  int qx = (lin < 256) ? (15 - (lin >> 5)) : ((lin - 256) >> 5);
  int q0 = qx * 128;
  int tid = threadIdx.x;
  int w = tid >> 6, l = tid & 63, l15 = l & 15, l4 = l >> 4;
  int qb = q0 + w * 32;            // wave owns 32 q-rows

  __shared__ u16 Ks[64][164];      // 328B row stride: <=2-way on frag reads
  __shared__ u16 Vs[160][68];      // 136B row stride: conflict-free reads
  __shared__ u16 Plds[4][32][68];  // per-wave P tile (32 rows)

  const u16* Qh = Qr + (size_t)h * S_LEN * HDIM;
  const u16* Kh = Kr + (size_t)h * S_LEN * HDIM;
  const u16* Vh = Vt + (size_t)h * HDIM * S_LEN;

  bf16x8 aQ[2][5];
#pragma unroll
  for (int mi = 0; mi < 2; mi++)
#pragma unroll
    for (int kc = 0; kc < 5; kc++)
      aQ[mi][kc] = *(const bf16x8*)&Qh[(size_t)(qb + mi * 16 + l15) * HDIM + kc * 32 + l4 * 8];

  f32x4 accO[2][10];
#pragma unroll
  for (int mi = 0; mi < 2; mi++)
#pragma unroll
    for (int dt = 0; dt < 10; dt++) accO[mi][dt] = f32x4{0.f, 0.f, 0.f, 0.f};
  float mrun[2][4], lrun[2][4];
#pragma unroll
  for (int mi = 0; mi < 2; mi++)
#pragma unroll
    for (int r = 0; r < 4; r++) { mrun[mi][r] = -1e30f; lrun[mi][r] = 0.f; }

  const float c2 = 0.07905694150420949f * 1.44269504088896f;  // 1/sqrt(160)*log2(e)
  int Tend = 2 * qx + 2;           // k tiles cover k <= q0+127

  // Staging map: 2560 16B-chunks = K tile (1280: 64 rows x 20) then V tile
  // (1280: 160 rows x 8). 256 threads -> 10 chunks each; 1280 % 256 == 0 so
  // the K/V split is wave-aligned (no divergence inside an i-step).
  {
    uint4 rg[10];
#pragma unroll
    for (int i = 0; i < 10; i++) {
      int u = tid + 256 * i;
      if (u < 1280) { int row = u / 20, c = u % 20;
        rg[i] = *(const uint4*)&Kh[(size_t)row * HDIM + c * 8]; }
      else { int v = u - 1280; int row = v >> 3, c = v & 7;
        rg[i] = *(const uint4*)&Vh[(size_t)row * S_LEN + c * 8]; }
    }
#pragma unroll
    for (int i = 0; i < 10; i++) {
      int u = tid + 256 * i;
      if (u < 1280) { int row = u / 20, c = u % 20; *(uint4*)&Ks[row][c * 8] = rg[i]; }
      else { int v = u - 1280; int row = v >> 3, c = v & 7; *(uint4*)&Vs[row][c * 8] = rg[i]; }
    }
  }
  __syncthreads();

  for (int t = 0; t < Tend; ++t) {
    int k0 = t * 64;
    bool more = (t + 1 < Tend);
    uint4 rg[10];
    if (more) {                     // issue next-tile loads early (T14)
      int k1 = k0 + 64;
#pragma unroll
      for (int i = 0; i < 10; i++) {
        int u = tid + 256 * i;
        if (u < 1280) { int row = u / 20, c = u % 20;
          rg[i] = *(const uint4*)&Kh[(size_t)(k1 + row) * HDIM + c * 8]; }
        else { int v = u - 1280; int row = v >> 3, c = v & 7;
          rg[i] = *(const uint4*)&Vh[(size_t)row * S_LEN + k1 + c * 8]; }
      }
    }

    if (k0 <= qb + 31) {            // wave-active (causal tile skip)
      f32x4 s_[2][4];
#pragma unroll
      for (int mi = 0; mi < 2; mi++)
#pragma unroll
        for (int nt = 0; nt < 4; nt++) s_[mi][nt] = f32x4{0.f, 0.f, 0.f, 0.f};

#pragma unroll
      for (int kc = 0; kc < 5; kc++) {
        bf16x8 bK[4];
#pragma unroll
        for (int nt = 0; nt < 4; nt++)
          bK[nt] = *(const bf16x8*)&Ks[nt * 16 + l15][kc * 32 + l4 * 8];
        __builtin_amdgcn_s_setprio(1);
#pragma unroll
        for (int mi = 0; mi < 2; mi++)
#pragma unroll
          for (int nt = 0; nt < 4; nt++)
            s_[mi][nt] = mfma16(aQ[mi][kc], bK[nt], s_[mi][nt]);
        __builtin_amdgcn_s_setprio(0);
      }

      if (k0 + 63 > qb) {           // diagonal-region mask
#pragma unroll
        for (int mi = 0; mi < 2; mi++)
#pragma unroll
          for (int nt = 0; nt < 4; nt++)
#pragma unroll
            for (int r = 0; r < 4; r++) {
              int kk = k0 + nt * 16 + l15;
              int qq = qb + mi * 16 + l4 * 4 + r;
              if (kk > qq) s_[mi][nt][r] = -1e30f;
            }
      }

#pragma unroll
      for (int mi = 0; mi < 2; mi++) {
        float sf[4];
#pragma unroll
        for (int r = 0; r < 4; r++) {
          float v = fmaxf(fmaxf(s_[mi][0][r], s_[mi][1][r]), fmaxf(s_[mi][2][r], s_[mi][3][r]));
#pragma unroll
          for (int m = 1; m <= 8; m <<= 1) v = fmaxf(v, __shfl_xor(v, m));
          float mnew = fmaxf(mrun[mi][r], v);
          sf[r] = exp2f((mrun[mi][r] - mnew) * c2);
          mrun[mi][r] = mnew;
        }
        float rsum[4] = {0.f, 0.f, 0.f, 0.f};
#pragma unroll
        for (int nt = 0; nt < 4; nt++)
#pragma unroll
          for (int r = 0; r < 4; r++) {
            float p = exp2f((s_[mi][nt][r] - mrun[mi][r]) * c2);
            s_[mi][nt][r] = p;
            rsum[r] += p;
          }
#pragma unroll
        for (int r = 0; r < 4; r++) {
          float v = rsum[r];
#pragma unroll
          for (int m = 1; m <= 8; m <<= 1) v += __shfl_xor(v, m);
          lrun[mi][r] = lrun[mi][r] * sf[r] + v;
        }
#pragma unroll
        for (int dt = 0; dt < 10; dt++)
#pragma unroll
          for (int r = 0; r < 4; r++) accO[mi][dt][r] *= sf[r];
#pragma unroll
        for (int nt = 0; nt < 4; nt++)
#pragma unroll
          for (int r = 0; r < 4; r++)
            Plds[w][mi * 16 + l4 * 4 + r][nt * 16 + l15] = f2bf(s_[mi][nt][r]);
      }

      // PV: A = P (wave-local LDS), B = V rows (block LDS)
#pragma unroll
      for (int kc = 0; kc < 2; kc++) {
        bf16x8 aP[2];
#pragma unroll
        for (int mi = 0; mi < 2; mi++)
          aP[mi] = *(const bf16x8*)&Plds[w][mi * 16 + l15][kc * 32 + l4 * 8];
        bf16x8 bV[10];
#pragma unroll
        for (int dt = 0; dt < 10; dt++)
          bV[dt] = *(const bf16x8*)&Vs[dt * 16 + l15][kc * 32 + l4 * 8];
        __builtin_amdgcn_s_setprio(1);
#pragma unroll
        for (int dt = 0; dt < 10; dt++) {
          accO[0][dt] = mfma16(aP[0], bV[dt], accO[0][dt]);
          accO[1][dt] = mfma16(aP[1], bV[dt], accO[1][dt]);
        }
        __builtin_amdgcn_s_setprio(0);
      }
    }

    __builtin_amdgcn_s_barrier();   // raw: prefetch rg stays in flight
    if (more) {
#pragma unroll
      for (int i = 0; i < 10; i++) {
        int u = tid + 256 * i;
        if (u < 1280) { int row = u / 20, c = u % 20; *(uint4*)&Ks[row][c * 8] = rg[i]; }
        else { int v = u - 1280; int row = v >> 3, c = v & 7; *(uint4*)&Vs[row][c * 8] = rg[i]; }
      }
      asm volatile("s_waitcnt lgkmcnt(0)" ::: "memory");  // writes visible to other waves
    }
    __builtin_amdgcn_s_barrier();
  }

#pragma unroll
  for (int mi = 0; mi < 2; mi++) {
    float inv[4];
#pragma unroll
    for (int r = 0; r < 4; r++) inv[r] = 1.0f / lrun[mi][r];
#pragma unroll
    for (int dt = 0; dt < 10; dt++)
#pragma unroll
      for (int r = 0; r < 4; r++) {
        int q = qb + mi * 16 + l4 * 4 + r;
        ctx[(size_t)q * HID + h * HDIM + dt * 16 + l15] = f2bf(accO[mi][dt][r] * inv[r]);
      }
  }
}

// -----------------------------------------------------------------------------
extern "C" void kernel_launch(void* const* d_in, const int* in_sizes, int n_in,
                              void* d_out, int out_size, void* d_ws, size_t ws_size,
                              hipStream_t stream) {
  const float* hs    = (const float*)d_in[0];
  const float* resid = (const float*)d_in[1];
  // d_in[2] = attention_mask (causal triu) — implied by kernel, ignored
  const float* Wq  = (const float*)d_in[3];
  const float* Wkv = (const float*)d_in[4];
  const float* Wd  = (const float*)d_in[5];
  const float* bd  = (const float*)d_in[6];
  float* out = (float*)d_out;

  char* ws = (char*)d_ws;
  const size_t SH = (size_t)S_LEN * HID;          // 10,485,760
  u16* Xb     = (u16*)(ws);                        size_t off = SH * 2;
  u16* Wqkvb  = (u16*)(ws + off);                  off += (size_t)3 * HID * HID * 2; // [Wq rows | Wkv rows]
  u16* Wdb    = (u16*)(ws + off);                  off += (size_t)HID * HID * 2;
  u16* QKVraw = (u16*)(ws + off);                  off += (size_t)S_LEN * NQKV * 2;  // [2048][15360]
  u16* Qr     = (u16*)(ws + off);                  off += SH * 2;
  u16* Kr     = (u16*)(ws + off);                  off += SH * 2;
  u16* Vt     = (u16*)(ws + off);                  off += SH * 2;
  u16* ctx    = (u16*)(ws + off);                  off += SH * 2;
  float2* tab = (float2*)(ws + off);               off += (size_t)S_LEN * 80 * 8;

  // 1) one fused f32->bf16 pass: hs + Wq + Wkv + Wd
  cvt_all_kernel<<<2048, 256, 0, stream>>>(hs, Wq, Wkv, Wd, Xb, Wqkvb, Wdb);

  // 2) RoPE table
  rope_table_kernel<<<64, 256, 0, stream>>>(tab);

  // 3) fused QKV projection: [2048,15360] = Xb @ [Wq|Wkv]^T  (256x128 tiles)
  gemm256<0><<<dim3(NQKV / 128, S_LEN / 256), 512, 0, stream>>>(
      Xb, Wqkvb, QKVraw, S_LEN, NQKV, HID, nullptr, nullptr);

  // 4) RoPE Q+K in one launch; V transpose
  rope_apply2_kernel<<<2 * S_LEN * NHEAD * 80 / 256, 256, 0, stream>>>(QKVraw, tab, Qr, Kr);
  vtrans_kernel<<<dim3(S_LEN / 64, NHEAD), 256, 0, stream>>>(QKVraw + HID + HDIM, Vt, NQKV);

  // 5) attention (4 waves x 32 q-rows, balanced pairing, raw barriers)
  attn_kernel<<<512, 256, 0, stream>>>(Qr, Kr, Vt, ctx);

  // 6) output projection + bias + residual (128² tile: 640 blocks fill the GPU)
  gemm_bt<1><<<dim3(HID / 128, S_LEN / 128), 256, 0, stream>>>(
      ctx, Wdb, out, S_LEN, HID, HID, bd, resid);
}